// Round 1
// baseline (12504.070 us; speedup 1.0000x reference)
//
#include <hip/hip_runtime.h>
#include <hip/hip_bf16.h>
#include <math.h>

// Problem constants
#define B_   256
#define NP_  3
#define LAT_ 512
#define TXT_ 768
#define D_   768
#define NL_  6
#define DI_  1536   // 2*D... no: 2*D=1536
#define DS_  16
#define DC_  4
#define DTR_ 48
#define L_   5      // time + text + 3 parts
#define M_   (B_*L_)  // 1280 rows for layer GEMMs
#define EPS_ 1e-5f

// ---------------- workspace layout (float offsets) ----------------
#define OFF_X     0u                 // B*5*D          = 983040
#define OFF_TC    983040u            // B*D            = 196608
#define OFF_CAT1  1179648u           // B*5*2D         = 1966080 (zfeat & znorm alias)
#define OFF_XT    3145728u           // B*5*D          = 983040  (temb aliases)
#define OFF_XZ    4128768u           // B*5*2DI        = 3932160 (yhat aliases)
#define OFF_UC    8060928u           // B*5*DI         = 1966080
#define OFF_XDBL  10027008u          // B*5*80         = 102400
#define OFF_DTB   10129408u          // B*5*DI         = 1966080
#define OFF_YMAM  12095488u          // B*5*DI         = 1966080 (xo aliases)
#define OFF_CAT2  14061568u          // B*5*2D         = 1966080
// total 16027648 floats = 64.1 MB

__device__ __forceinline__ float sigm(float v) { return 1.f / (1.f + expf(-v)); }

// ---------------- generic tiled fp32 GEMM: C[m,n] = sum_k A[m,k]*W[n,k] (+bias, +epi) ----
// epi: 0 = none, 1 = silu, 2 = softplus
__global__ __launch_bounds__(256) void gemm_kernel(
    const float* __restrict__ A, int lda,
    const float* __restrict__ W,
    const float* __restrict__ bias,
    float* __restrict__ C, int ldc,
    int M, int N, int K, int epi)
{
    __shared__ float As[16][65];
    __shared__ float Ws[16][65];
    const int tid = threadIdx.x;
    const int tx = tid & 15, ty = tid >> 4;
    const int m0 = blockIdx.y * 64, n0 = blockIdx.x * 64;
    float acc[4][4] = {};

    for (int k0 = 0; k0 < K; k0 += 16) {
#pragma unroll
        for (int i = 0; i < 4; ++i) {
            int idx = tid * 4 + i;          // 0..1023
            int r = idx >> 4, c = idx & 15;
            int gm = m0 + r, gk = k0 + c;
            As[c][r] = (gm < M && gk < K) ? A[(size_t)gm * lda + gk] : 0.f;
            int gn = n0 + r;
            Ws[c][r] = (gn < N && gk < K) ? W[(size_t)gn * K + gk] : 0.f;
        }
        __syncthreads();
#pragma unroll
        for (int kk = 0; kk < 16; ++kk) {
            float a[4], b[4];
#pragma unroll
            for (int i = 0; i < 4; ++i) a[i] = As[kk][ty * 4 + i];
#pragma unroll
            for (int j = 0; j < 4; ++j) b[j] = Ws[kk][tx * 4 + j];
#pragma unroll
            for (int i = 0; i < 4; ++i)
#pragma unroll
                for (int j = 0; j < 4; ++j)
                    acc[i][j] = fmaf(a[i], b[j], acc[i][j]);
        }
        __syncthreads();
    }
#pragma unroll
    for (int i = 0; i < 4; ++i) {
        int m = m0 + ty * 4 + i;
        if (m >= M) continue;
#pragma unroll
        for (int j = 0; j < 4; ++j) {
            int n = n0 + tx * 4 + j;
            if (n >= N) continue;
            float v = acc[i][j] + (bias ? bias[n] : 0.f);
            if (epi == 1)      v = v * sigm(v);                                  // silu
            else if (epi == 2) v = fmaxf(v, 0.f) + log1pf(expf(-fabsf(v)));      // softplus
            C[(size_t)m * ldc + n] = v;
        }
    }
}

// ---------------- timestep embedding: temb[b, 0:384]=cos, [384:768]=sin -------------
__global__ void temb_kernel(const int* __restrict__ ts, float* __restrict__ temb)
{
    int idx = blockIdx.x * blockDim.x + threadIdx.x;   // B*384
    if (idx >= B_ * 384) return;
    int j = idx % 384, b = idx / 384;
    float f = expf(-logf(10000.f) * (float)j / 384.f);
    float targ = (float)ts[b] * f;
    temb[(size_t)b * D_ + j]       = cosf(targ);
    temb[(size_t)b * D_ + 384 + j] = sinf(targ);
}

// ---------------- scatter z_feat + part_emb, add PE, save text_cond ----------------
__global__ void finalize_embed_kernel(float* __restrict__ x,
                                      const float* __restrict__ zfeat,
                                      const float* __restrict__ part_emb,
                                      float* __restrict__ tc)
{
    int idx = blockIdx.x * blockDim.x + threadIdx.x;   // B*5*768
    if (idx >= B_ * L_ * D_) return;
    int d = idx % D_;
    int bl = idx / D_;
    int l = bl % L_, b = bl / L_;
    float v;
    if (l >= 2) v = zfeat[((size_t)(b * 3 + (l - 2))) * D_ + d] + part_emb[(size_t)(l - 2) * D_ + d];
    else        v = x[idx];
    int j = d >> 1;
    float dv = expf((float)(2 * j) * (-logf(10000.f) / (float)D_));
    float ang = (float)l * dv;
    v += (d & 1) ? cosf(ang) : sinf(ang);
    x[idx] = v;
    if (l == 1) tc[(size_t)b * D_ + d] = v;
}

// ---------------- fill y_rep into cat1 right half ----------------
__global__ void fill_yrep_kernel(float* __restrict__ cat1, const float* __restrict__ tc)
{
    int idx = blockIdx.x * blockDim.x + threadIdx.x;   // B*5*768
    if (idx >= B_ * L_ * D_) return;
    int d = idx % D_;
    int bl = idx / D_;
    int b = bl / L_;
    cat1[(size_t)bl * (2 * D_) + D_ + d] = tc[(size_t)b * D_ + d];
}

// ---------------- y_gate = y_rep * sigmoid(yhat) into cat1 right half -------------
__global__ void gate_kernel(float* __restrict__ cat1, const float* __restrict__ tc,
                            const float* __restrict__ yhat)
{
    int idx = blockIdx.x * blockDim.x + threadIdx.x;   // B*5*768
    if (idx >= B_ * L_ * D_) return;
    int d = idx % D_;
    int bl = idx / D_;
    int b = bl / L_;
    cat1[(size_t)bl * (2 * D_) + D_ + d] = tc[(size_t)b * D_ + d] * sigm(yhat[idx]);
}

// ---------------- causal depthwise conv (DC=4) + SiLU; dir=1 is anti-causal -------
__global__ void conv_silu_kernel(const float* __restrict__ xz,
                                 const float* __restrict__ cw,
                                 const float* __restrict__ cb,
                                 float* __restrict__ uc, int dir)
{
    int idx = blockIdx.x * blockDim.x + threadIdx.x;   // B*5*DI
    if (idx >= B_ * L_ * DI_) return;
    int ch = idx % DI_;
    int bl = idx / DI_;
    int l = bl % L_, b = bl / L_;
    float v = cb[ch];
#pragma unroll
    for (int k = 0; k < DC_; ++k) {
        int lp = dir ? (l + 3 - k) : (l + k - 3);
        if (lp >= 0 && lp < L_)
            v += cw[(size_t)ch * DC_ + k] * xz[((size_t)(b * L_ + lp)) * (2 * DI_) + ch];
    }
    uc[idx] = v * sigm(v);
}

// ---------------- selective scan over L=5, DS=16 state per channel ----------------
__global__ void scan_kernel(const float* __restrict__ dtb,
                            const float* __restrict__ uc,
                            const float* __restrict__ xdbl,
                            const float* __restrict__ xz,
                            const float* __restrict__ Alog,
                            const float* __restrict__ Dp,
                            float* __restrict__ ymam, int dir)
{
    int ch = blockIdx.x * blockDim.x + threadIdx.x;
    int b = blockIdx.y;
    if (ch >= DI_) return;
    float A[DS_], h[DS_];
#pragma unroll
    for (int s = 0; s < DS_; ++s) { A[s] = -expf(Alog[(size_t)ch * DS_ + s]); h[s] = 0.f; }
    float Dv = Dp[ch];
    for (int t = 0; t < L_; ++t) {
        int l = dir ? (L_ - 1 - t) : t;
        size_t base = (size_t)(b * L_ + l);
        float dtv = dtb[base * DI_ + ch];
        float ucv = uc[base * DI_ + ch];
        float du = dtv * ucv;
        float y = 0.f;
#pragma unroll
        for (int s = 0; s < DS_; ++s) {
            h[s] = h[s] * expf(dtv * A[s]) + du * xdbl[base * 80 + 48 + s];
            y += h[s] * xdbl[base * 80 + 64 + s];
        }
        float zv = xz[base * (2 * DI_) + DI_ + ch];
        ymam[base * DI_ + ch] = (y + Dv * ucv) * (zv * sigm(zv));
    }
}

// ---------------- block reduce helper (256 threads) ----------------
__device__ __forceinline__ float block_sum(float v)
{
    __shared__ float sd[4];
#pragma unroll
    for (int o = 1; o < 64; o <<= 1) v += __shfl_xor(v, o, 64);
    int lane = threadIdx.x & 63, wid = threadIdx.x >> 6;
    if (lane == 0) sd[wid] = v;
    __syncthreads();
    v = sd[0] + sd[1] + sd[2] + sd[3];
    __syncthreads();
    return v;
}

// ---------------- LN(xo + x) -> x (residual layernorm) ----------------
__global__ __launch_bounds__(256) void ln_residual_kernel(
    const float* __restrict__ xo, float* __restrict__ x,
    const float* __restrict__ g, const float* __restrict__ bt)
{
    int row = blockIdx.x;                     // B*5
    const float* pa = xo + (size_t)row * D_;
    float* px = x + (size_t)row * D_;
    float v[3];
    float s = 0.f;
#pragma unroll
    for (int i = 0; i < 3; ++i) { int d = threadIdx.x + 256 * i; v[i] = pa[d] + px[d]; s += v[i]; }
    float mean = block_sum(s) * (1.f / (float)D_);
    float sq = 0.f;
#pragma unroll
    for (int i = 0; i < 3; ++i) { float t = v[i] - mean; sq += t * t; }
    float var = block_sum(sq) * (1.f / (float)D_);
    float inv = rsqrtf(var + EPS_);
#pragma unroll
    for (int i = 0; i < 3; ++i) {
        int d = threadIdx.x + 256 * i;
        px[d] = (v[i] - mean) * inv * g[d] + bt[d];
    }
}

// ---------------- final LN: rows b*3+p from x[:,2+p,:] -> znorm ----------------
__global__ __launch_bounds__(256) void ln_out_kernel(
    const float* __restrict__ x, const float* __restrict__ g,
    const float* __restrict__ bt, float* __restrict__ znorm)
{
    int row = blockIdx.x;                     // B*3
    int b = row / 3, p = row % 3;
    const float* pa = x + ((size_t)(b * L_ + 2 + p)) * D_;
    float* po = znorm + (size_t)row * D_;
    float v[3];
    float s = 0.f;
#pragma unroll
    for (int i = 0; i < 3; ++i) { int d = threadIdx.x + 256 * i; v[i] = pa[d]; s += v[i]; }
    float mean = block_sum(s) * (1.f / (float)D_);
    float sq = 0.f;
#pragma unroll
    for (int i = 0; i < 3; ++i) { float t = v[i] - mean; sq += t * t; }
    float var = block_sum(sq) * (1.f / (float)D_);
    float inv = rsqrtf(var + EPS_);
#pragma unroll
    for (int i = 0; i < 3; ++i) {
        int d = threadIdx.x + 256 * i;
        po[d] = (v[i] - mean) * inv * g[d] + bt[d];
    }
}

extern "C" void kernel_launch(void* const* d_in, const int* in_sizes, int n_in,
                              void* d_out, int out_size, void* d_ws, size_t ws_size,
                              hipStream_t stream)
{
    const float* z_noisy  = (const float*)d_in[0];
    const float* text_emb = (const float*)d_in[1];
    const float* zin_w    = (const float*)d_in[2];
    const float* zin_b    = (const float*)d_in[3];
    const float* tin_w    = (const float*)d_in[4];
    const float* tin_b    = (const float*)d_in[5];
    const float* time_w   = (const float*)d_in[6];
    const float* time_b   = (const float*)d_in[7];
    const float* part_emb = (const float*)d_in[8];
    const float* local_w  = (const float*)d_in[9];
    const float* local_b  = (const float*)d_in[10];
    const float* f_w      = (const float*)d_in[11];
    const float* f_b      = (const float*)d_in[12];
    const float* fuse_w   = (const float*)d_in[13];
    const float* fuse_b   = (const float*)d_in[14];
    const float* final_w  = (const float*)d_in[15];
    const float* final_b  = (const float*)d_in[16];
    const float* ln_g     = (const float*)d_in[17];
    const float* ln_b     = (const float*)d_in[18];
    const float* m_in_w   = (const float*)d_in[19];
    const float* m_conv_w = (const float*)d_in[20];
    const float* m_conv_b = (const float*)d_in[21];
    const float* m_xproj_w= (const float*)d_in[22];
    const float* m_dt_w   = (const float*)d_in[23];
    const float* m_dt_b   = (const float*)d_in[24];
    const float* m_Alog   = (const float*)d_in[25];
    const float* m_Dp     = (const float*)d_in[26];
    const float* m_out_w  = (const float*)d_in[27];
    const float* oln_g    = (const float*)d_in[28];
    const float* oln_b    = (const float*)d_in[29];
    const float* zout_w   = (const float*)d_in[30];
    const float* zout_b   = (const float*)d_in[31];
    const int*   timestep = (const int*)d_in[32];

    float* ws = (float*)d_ws;
    float* x     = ws + OFF_X;
    float* tc    = ws + OFF_TC;
    float* cat1  = ws + OFF_CAT1;      // also zfeat (start) and znorm (end)
    float* xt    = ws + OFF_XT;        // also temb (start)
    float* xz    = ws + OFF_XZ;        // also yhat
    float* uc    = ws + OFF_UC;
    float* xdbl  = ws + OFF_XDBL;
    float* dtb   = ws + OFF_DTB;
    float* ymam  = ws + OFF_YMAM;      // also xo
    float* cat2  = ws + OFF_CAT2;

    float* zfeat = cat1;
    float* temb  = xt;
    float* yhat  = xz;
    float* xo    = ymam;
    float* znorm = cat1;

    auto gemm = [&](const float* A, int lda, const float* W, const float* bias,
                    float* C, int ldc, int M, int N, int K, int epi) {
        dim3 g((N + 63) / 64, (M + 63) / 64);
        hipLaunchKernelGGL(gemm_kernel, g, dim3(256), 0, stream,
                           A, lda, W, bias, C, ldc, M, N, K, epi);
    };
    auto ew = [&](int n) { return dim3((n + 255) / 256); };

    // ---------- embedding ----------
    hipLaunchKernelGGL(temb_kernel, ew(B_ * 384), dim3(256), 0, stream, timestep, temb);
    // time_feat -> x rows (b,0)
    gemm(temb, D_, time_w, time_b, x + 0 * D_, L_ * D_, B_, D_, D_, 0);
    // text_feat -> x rows (b,1)
    gemm(text_emb, TXT_, tin_w, tin_b, x + 1 * D_, L_ * D_, B_, D_, TXT_, 0);
    // z_feat -> zfeat (B*3, D)
    gemm(z_noisy, LAT_, zin_w, zin_b, zfeat, D_, B_ * NP_, D_, LAT_, 0);
    hipLaunchKernelGGL(finalize_embed_kernel, ew(B_ * L_ * D_), dim3(256), 0, stream,
                       x, zfeat, part_emb, tc);

    // ---------- layers ----------
    for (int i = 0; i < NL_; ++i) {
        // xl = silu(x @ local_w^T + local_b) -> cat1 left half
        gemm(x, D_, local_w + (size_t)i * D_ * D_, local_b + (size_t)i * D_,
             cat1, 2 * D_, M_, D_, D_, 1);
        // y_rep -> cat1 right half
        hipLaunchKernelGGL(fill_yrep_kernel, ew(B_ * L_ * D_), dim3(256), 0, stream, cat1, tc);
        // yhat = cat1 @ f_w^T + f_b
        gemm(cat1, 2 * D_, f_w + (size_t)i * D_ * 2 * D_, f_b + (size_t)i * D_,
             yhat, D_, M_, D_, 2 * D_, 0);
        // y_gate -> cat1 right half
        hipLaunchKernelGGL(gate_kernel, ew(B_ * L_ * D_), dim3(256), 0, stream, cat1, tc, yhat);
        // xt = cat1 @ fuse_w^T + fuse_b
        gemm(cat1, 2 * D_, fuse_w + (size_t)i * D_ * 2 * D_, fuse_b + (size_t)i * D_,
             xt, D_, M_, D_, 2 * D_, 0);

        for (int dir = 0; dir < 2; ++dir) {
            size_t mo = (size_t)(i * 2 + dir);
            // xz = xt @ in_w^T   (B*5, 3072)
            gemm(xt, D_, m_in_w + mo * 2 * DI_ * D_, nullptr, xz, 2 * DI_, M_, 2 * DI_, D_, 0);
            // conv + silu -> uc
            hipLaunchKernelGGL(conv_silu_kernel, ew(B_ * L_ * DI_), dim3(256), 0, stream,
                               xz, m_conv_w + mo * DI_ * DC_, m_conv_b + mo * DI_, uc, dir);
            // xdbl = uc @ xproj^T   (B*5, 80)
            gemm(uc, DI_, m_xproj_w + mo * 80 * DI_, nullptr, xdbl, 80, M_, 80, DI_, 0);
            // dt = softplus(xdbl[:, :48] @ dt_w^T + dt_b)  (B*5, 1536)
            gemm(xdbl, 80, m_dt_w + mo * DI_ * DTR_, m_dt_b + mo * DI_,
                 dtb, DI_, M_, DI_, DTR_, 2);
            // scan -> ymam (already gated by silu(z) and + Dp*uc)
            hipLaunchKernelGGL(scan_kernel, dim3(DI_ / 256, B_), dim3(256), 0, stream,
                               dtb, uc, xdbl, xz, m_Alog + mo * DI_ * DS_, m_Dp + mo * DI_,
                               ymam, dir);
            // out = ymam @ out_w^T -> cat2 half
            gemm(ymam, DI_, m_out_w + mo * D_ * DI_, nullptr,
                 cat2 + (size_t)dir * D_, 2 * D_, M_, D_, DI_, 0);
        }
        // xo = cat2 @ final_w^T + final_b
        gemm(cat2, 2 * D_, final_w + (size_t)i * D_ * 2 * D_, final_b + (size_t)i * D_,
             xo, D_, M_, D_, 2 * D_, 0);
        // x = LN(xo + x)
        hipLaunchKernelGGL(ln_residual_kernel, dim3(M_), dim3(256), 0, stream,
                           xo, x, ln_g + (size_t)i * D_, ln_b + (size_t)i * D_);
    }

    // ---------- output head ----------
    hipLaunchKernelGGL(ln_out_kernel, dim3(B_ * NP_), dim3(256), 0, stream,
                       x, oln_g, oln_b, znorm);
    gemm(znorm, D_, zout_w, zout_b, (float*)d_out, LAT_, B_ * NP_, LAT_, D_, 0);
}

// Round 2
// 3428.899 us; speedup vs baseline: 3.6467x; 3.6467x over previous
//
#include <hip/hip_runtime.h>
#include <hip/hip_bf16.h>
#include <math.h>

// Problem constants
#define B_   256
#define NP_  3
#define LAT_ 512
#define TXT_ 768
#define D_   768
#define NL_  6
#define DI_  1536
#define DS_  16
#define DC_  4
#define DTR_ 48
#define L_   5
#define M_   (B_*L_)
#define EPS_ 1e-5f

// ---------------- workspace layout (float offsets) ----------------
#define OFF_X     0u
#define OFF_TC    983040u
#define OFF_CAT1  1179648u
#define OFF_XT    3145728u
#define OFF_XZ    4128768u
#define OFF_UC    8060928u
#define OFF_XDBL  10027008u
#define OFF_DTB   10129408u
#define OFF_YMAM  12095488u
#define OFF_CAT2  14061568u
// total 16027648 floats = 64.1 MB

typedef __attribute__((ext_vector_type(4))) float floatx4;
typedef __attribute__((ext_vector_type(8))) short short8;
typedef __attribute__((ext_vector_type(4))) unsigned short ushort4v;

__device__ __forceinline__ float sigm(float v) { return 1.f / (1.f + expf(-v)); }

__device__ __forceinline__ unsigned short bf16rn(float f) {
    unsigned int u = __builtin_bit_cast(unsigned int, f);
    u = (u + 0x7fffu + ((u >> 16) & 1u)) >> 16;
    return (unsigned short)u;
}

// ============ MFMA bf16 GEMM: C[m,n] = sum_k A[m,k]*W[n,k] (+bias, +epi) ============
// A: M x K fp32 (lda), W: N x K fp32 (row-major), C: M x N fp32 (ldc)
// epi: 0 none, 1 silu, 2 softplus. Converts fp32->bf16 inline during LDS staging.
// LDS row = 40 bf16 (80B): rows 0..7 cover all 32 banks -> 2-way (free) on ds_read_b128.
template<int BM, int BN, bool GUARD>
__global__ __launch_bounds__(256) void gemm_mfma_kernel(
    const float* __restrict__ A, int lda,
    const float* __restrict__ W,
    const float* __restrict__ bias,
    float* __restrict__ C, int ldc,
    int M, int N, int K, int epi)
{
    constexpr int LA = BM / 32;    // float4 loads per thread for A tile (BM x 32)
    constexpr int LB = BN / 32;
    constexpr int FRM = BM / 32;   // 16x16 frags per wave in M (wave tile = BM/2 x BN/2)
    constexpr int FRN = BN / 32;

    __shared__ short lds[2][(BM + BN) * 40];

    const int tid = threadIdx.x;
    const int m0 = blockIdx.y * BM, n0 = blockIdx.x * BN;
    const int w = tid >> 6, lane = tid & 63;
    const int wr = w >> 1, wc = w & 1;
    const int lrow = lane & 15;
    const int lk = (lane >> 4) << 3;   // 0,8,16,24 (bf16 units)

    floatx4 ra[LA], rb[LB];
    floatx4 acc[FRM][FRN] = {};

    auto gload = [&](int k0) {
#pragma unroll
        for (int i = 0; i < LA; ++i) {
            int idx = tid + 256 * i; int r = idx >> 3, cb = (idx & 7) * 4;
            if constexpr (GUARD) {
                floatx4 v = {0.f, 0.f, 0.f, 0.f};
                if (m0 + r < M) {
#pragma unroll
                    for (int e = 0; e < 4; ++e)
                        if (k0 + cb + e < K) v[e] = A[(size_t)(m0 + r) * lda + k0 + cb + e];
                }
                ra[i] = v;
            } else {
                ra[i] = *(const floatx4*)(A + (size_t)(m0 + r) * lda + k0 + cb);
            }
        }
#pragma unroll
        for (int i = 0; i < LB; ++i) {
            int idx = tid + 256 * i; int r = idx >> 3, cb = (idx & 7) * 4;
            if constexpr (GUARD) {
                floatx4 v = {0.f, 0.f, 0.f, 0.f};
                if (n0 + r < N) {
#pragma unroll
                    for (int e = 0; e < 4; ++e)
                        if (k0 + cb + e < K) v[e] = W[(size_t)(n0 + r) * K + k0 + cb + e];
                }
                rb[i] = v;
            } else {
                rb[i] = *(const floatx4*)(W + (size_t)(n0 + r) * K + k0 + cb);
            }
        }
    };
    auto lstore = [&](int buf) {
        short* pa = lds[buf];
        short* pb = lds[buf] + BM * 40;
#pragma unroll
        for (int i = 0; i < LA; ++i) {
            int idx = tid + 256 * i; int r = idx >> 3, cb = (idx & 7) * 4;
            ushort4v p = { bf16rn(ra[i][0]), bf16rn(ra[i][1]), bf16rn(ra[i][2]), bf16rn(ra[i][3]) };
            *(ushort4v*)(pa + r * 40 + cb) = p;
        }
#pragma unroll
        for (int i = 0; i < LB; ++i) {
            int idx = tid + 256 * i; int r = idx >> 3, cb = (idx & 7) * 4;
            ushort4v p = { bf16rn(rb[i][0]), bf16rn(rb[i][1]), bf16rn(rb[i][2]), bf16rn(rb[i][3]) };
            *(ushort4v*)(pb + r * 40 + cb) = p;
        }
    };

    const int nt = (K + 31) >> 5;
    gload(0);
    lstore(0);
    __syncthreads();
    int cur = 0;
    for (int t = 0; t < nt; ++t) {
        if (t + 1 < nt) gload((t + 1) << 5);
        const short* pa = lds[cur];
        const short* pb = lds[cur] + BM * 40;
        short8 af[FRM], bfv[FRN];
#pragma unroll
        for (int i = 0; i < FRM; ++i)
            af[i] = *(const short8*)(pa + (wr * (BM / 2) + i * 16 + lrow) * 40 + lk);
#pragma unroll
        for (int j = 0; j < FRN; ++j)
            bfv[j] = *(const short8*)(pb + (wc * (BN / 2) + j * 16 + lrow) * 40 + lk);
#pragma unroll
        for (int i = 0; i < FRM; ++i)
#pragma unroll
            for (int j = 0; j < FRN; ++j)
                acc[i][j] = __builtin_amdgcn_mfma_f32_16x16x32_bf16(af[i], bfv[j], acc[i][j], 0, 0, 0);
        if (t + 1 < nt) {
            lstore(cur ^ 1);
            __syncthreads();
            cur ^= 1;
        }
    }

    // epilogue: D layout col=lane&15, row=(lane>>4)*4+r
#pragma unroll
    for (int i = 0; i < FRM; ++i) {
        int row0 = m0 + wr * (BM / 2) + i * 16 + (lane >> 4) * 4;
#pragma unroll
        for (int j = 0; j < FRN; ++j) {
            int col = n0 + wc * (BN / 2) + j * 16 + lrow;
            if (GUARD && col >= N) continue;
            float bb = bias ? bias[col] : 0.f;
#pragma unroll
            for (int r = 0; r < 4; ++r) {
                if (GUARD && row0 + r >= M) continue;
                float v = acc[i][j][r] + bb;
                if (epi == 1)      v = v * sigm(v);
                else if (epi == 2) v = fmaxf(v, 0.f) + log1pf(expf(-fabsf(v)));
                C[(size_t)(row0 + r) * ldc + col] = v;
            }
        }
    }
}

// ---------------- timestep embedding ----------------
__global__ void temb_kernel(const int* __restrict__ ts, float* __restrict__ temb)
{
    int idx = blockIdx.x * blockDim.x + threadIdx.x;
    if (idx >= B_ * 384) return;
    int j = idx % 384, b = idx / 384;
    float f = expf(-logf(10000.f) * (float)j / 384.f);
    float targ = (float)ts[b] * f;
    temb[(size_t)b * D_ + j]       = cosf(targ);
    temb[(size_t)b * D_ + 384 + j] = sinf(targ);
}

// ---------------- scatter z_feat + part_emb, add PE, save text_cond ----------------
__global__ void finalize_embed_kernel(float* __restrict__ x,
                                      const float* __restrict__ zfeat,
                                      const float* __restrict__ part_emb,
                                      float* __restrict__ tc)
{
    int idx = blockIdx.x * blockDim.x + threadIdx.x;
    if (idx >= B_ * L_ * D_) return;
    int d = idx % D_;
    int bl = idx / D_;
    int l = bl % L_, b = bl / L_;
    float v;
    if (l >= 2) v = zfeat[((size_t)(b * 3 + (l - 2))) * D_ + d] + part_emb[(size_t)(l - 2) * D_ + d];
    else        v = x[idx];
    int j = d >> 1;
    float dv = expf((float)(2 * j) * (-logf(10000.f) / (float)D_));
    float ang = (float)l * dv;
    v += (d & 1) ? cosf(ang) : sinf(ang);
    x[idx] = v;
    if (l == 1) tc[(size_t)b * D_ + d] = v;
}

__global__ void fill_yrep_kernel(float* __restrict__ cat1, const float* __restrict__ tc)
{
    int idx = blockIdx.x * blockDim.x + threadIdx.x;
    if (idx >= B_ * L_ * D_) return;
    int d = idx % D_;
    int bl = idx / D_;
    int b = bl / L_;
    cat1[(size_t)bl * (2 * D_) + D_ + d] = tc[(size_t)b * D_ + d];
}

__global__ void gate_kernel(float* __restrict__ cat1, const float* __restrict__ tc,
                            const float* __restrict__ yhat)
{
    int idx = blockIdx.x * blockDim.x + threadIdx.x;
    if (idx >= B_ * L_ * D_) return;
    int d = idx % D_;
    int bl = idx / D_;
    int b = bl / L_;
    cat1[(size_t)bl * (2 * D_) + D_ + d] = tc[(size_t)b * D_ + d] * sigm(yhat[idx]);
}

__global__ void conv_silu_kernel(const float* __restrict__ xz,
                                 const float* __restrict__ cw,
                                 const float* __restrict__ cb,
                                 float* __restrict__ uc, int dir)
{
    int idx = blockIdx.x * blockDim.x + threadIdx.x;
    if (idx >= B_ * L_ * DI_) return;
    int ch = idx % DI_;
    int bl = idx / DI_;
    int l = bl % L_, b = bl / L_;
    float v = cb[ch];
#pragma unroll
    for (int k = 0; k < DC_; ++k) {
        int lp = dir ? (l + 3 - k) : (l + k - 3);
        if (lp >= 0 && lp < L_)
            v += cw[(size_t)ch * DC_ + k] * xz[((size_t)(b * L_ + lp)) * (2 * DI_) + ch];
    }
    uc[idx] = v * sigm(v);
}

__global__ void scan_kernel(const float* __restrict__ dtb,
                            const float* __restrict__ uc,
                            const float* __restrict__ xdbl,
                            const float* __restrict__ xz,
                            const float* __restrict__ Alog,
                            const float* __restrict__ Dp,
                            float* __restrict__ ymam, int dir)
{
    int ch = blockIdx.x * blockDim.x + threadIdx.x;
    int b = blockIdx.y;
    if (ch >= DI_) return;
    float A[DS_], h[DS_];
#pragma unroll
    for (int s = 0; s < DS_; ++s) { A[s] = -expf(Alog[(size_t)ch * DS_ + s]); h[s] = 0.f; }
    float Dv = Dp[ch];
    for (int t = 0; t < L_; ++t) {
        int l = dir ? (L_ - 1 - t) : t;
        size_t base = (size_t)(b * L_ + l);
        float dtv = dtb[base * DI_ + ch];
        float ucv = uc[base * DI_ + ch];
        float du = dtv * ucv;
        float y = 0.f;
#pragma unroll
        for (int s = 0; s < DS_; ++s) {
            h[s] = h[s] * expf(dtv * A[s]) + du * xdbl[base * 80 + 48 + s];
            y += h[s] * xdbl[base * 80 + 64 + s];
        }
        float zv = xz[base * (2 * DI_) + DI_ + ch];
        ymam[base * DI_ + ch] = (y + Dv * ucv) * (zv * sigm(zv));
    }
}

__device__ __forceinline__ float block_sum(float v)
{
    __shared__ float sd[4];
#pragma unroll
    for (int o = 1; o < 64; o <<= 1) v += __shfl_xor(v, o, 64);
    int lane = threadIdx.x & 63, wid = threadIdx.x >> 6;
    if (lane == 0) sd[wid] = v;
    __syncthreads();
    v = sd[0] + sd[1] + sd[2] + sd[3];
    __syncthreads();
    return v;
}

__global__ __launch_bounds__(256) void ln_residual_kernel(
    const float* __restrict__ xo, float* __restrict__ x,
    const float* __restrict__ g, const float* __restrict__ bt)
{
    int row = blockIdx.x;
    const float* pa = xo + (size_t)row * D_;
    float* px = x + (size_t)row * D_;
    float v[3];
    float s = 0.f;
#pragma unroll
    for (int i = 0; i < 3; ++i) { int d = threadIdx.x + 256 * i; v[i] = pa[d] + px[d]; s += v[i]; }
    float mean = block_sum(s) * (1.f / (float)D_);
    float sq = 0.f;
#pragma unroll
    for (int i = 0; i < 3; ++i) { float t = v[i] - mean; sq += t * t; }
    float var = block_sum(sq) * (1.f / (float)D_);
    float inv = rsqrtf(var + EPS_);
#pragma unroll
    for (int i = 0; i < 3; ++i) {
        int d = threadIdx.x + 256 * i;
        px[d] = (v[i] - mean) * inv * g[d] + bt[d];
    }
}

__global__ __launch_bounds__(256) void ln_out_kernel(
    const float* __restrict__ x, const float* __restrict__ g,
    const float* __restrict__ bt, float* __restrict__ znorm)
{
    int row = blockIdx.x;
    int b = row / 3, p = row % 3;
    const float* pa = x + ((size_t)(b * L_ + 2 + p)) * D_;
    float* po = znorm + (size_t)row * D_;
    float v[3];
    float s = 0.f;
#pragma unroll
    for (int i = 0; i < 3; ++i) { int d = threadIdx.x + 256 * i; v[i] = pa[d]; s += v[i]; }
    float mean = block_sum(s) * (1.f / (float)D_);
    float sq = 0.f;
#pragma unroll
    for (int i = 0; i < 3; ++i) { float t = v[i] - mean; sq += t * t; }
    float var = block_sum(sq) * (1.f / (float)D_);
    float inv = rsqrtf(var + EPS_);
#pragma unroll
    for (int i = 0; i < 3; ++i) {
        int d = threadIdx.x + 256 * i;
        po[d] = (v[i] - mean) * inv * g[d] + bt[d];
    }
}

extern "C" void kernel_launch(void* const* d_in, const int* in_sizes, int n_in,
                              void* d_out, int out_size, void* d_ws, size_t ws_size,
                              hipStream_t stream)
{
    const float* z_noisy  = (const float*)d_in[0];
    const float* text_emb = (const float*)d_in[1];
    const float* zin_w    = (const float*)d_in[2];
    const float* zin_b    = (const float*)d_in[3];
    const float* tin_w    = (const float*)d_in[4];
    const float* tin_b    = (const float*)d_in[5];
    const float* time_w   = (const float*)d_in[6];
    const float* time_b   = (const float*)d_in[7];
    const float* part_emb = (const float*)d_in[8];
    const float* local_w  = (const float*)d_in[9];
    const float* local_b  = (const float*)d_in[10];
    const float* f_w      = (const float*)d_in[11];
    const float* f_b      = (const float*)d_in[12];
    const float* fuse_w   = (const float*)d_in[13];
    const float* fuse_b   = (const float*)d_in[14];
    const float* final_w  = (const float*)d_in[15];
    const float* final_b  = (const float*)d_in[16];
    const float* ln_g     = (const float*)d_in[17];
    const float* ln_b     = (const float*)d_in[18];
    const float* m_in_w   = (const float*)d_in[19];
    const float* m_conv_w = (const float*)d_in[20];
    const float* m_conv_b = (const float*)d_in[21];
    const float* m_xproj_w= (const float*)d_in[22];
    const float* m_dt_w   = (const float*)d_in[23];
    const float* m_dt_b   = (const float*)d_in[24];
    const float* m_Alog   = (const float*)d_in[25];
    const float* m_Dp     = (const float*)d_in[26];
    const float* m_out_w  = (const float*)d_in[27];
    const float* oln_g    = (const float*)d_in[28];
    const float* oln_b    = (const float*)d_in[29];
    const float* zout_w   = (const float*)d_in[30];
    const float* zout_b   = (const float*)d_in[31];
    const int*   timestep = (const int*)d_in[32];

    float* ws = (float*)d_ws;
    float* x     = ws + OFF_X;
    float* tc    = ws + OFF_TC;
    float* cat1  = ws + OFF_CAT1;
    float* xt    = ws + OFF_XT;
    float* xz    = ws + OFF_XZ;
    float* uc    = ws + OFF_UC;
    float* xdbl  = ws + OFF_XDBL;
    float* dtb   = ws + OFF_DTB;
    float* ymam  = ws + OFF_YMAM;
    float* cat2  = ws + OFF_CAT2;

    float* zfeat = cat1;
    float* temb  = xt;
    float* yhat  = xz;
    float* xo    = ymam;
    float* znorm = cat1;

    auto gemm = [&](const float* A, int lda, const float* W, const float* bias,
                    float* C, int ldc, int M, int N, int K, int epi) {
        if (N >= 1536 && (N % 128) == 0 && (M % 128) == 0 && (K % 32) == 0) {
            dim3 g(N / 128, M / 128);
            gemm_mfma_kernel<128, 128, false><<<g, dim3(256), 0, stream>>>(
                A, lda, W, bias, C, ldc, M, N, K, epi);
        } else if ((N % 64) == 0 && (M % 64) == 0 && (K % 32) == 0) {
            dim3 g(N / 64, M / 64);
            gemm_mfma_kernel<64, 64, false><<<g, dim3(256), 0, stream>>>(
                A, lda, W, bias, C, ldc, M, N, K, epi);
        } else {
            dim3 g((N + 63) / 64, (M + 63) / 64);
            gemm_mfma_kernel<64, 64, true><<<g, dim3(256), 0, stream>>>(
                A, lda, W, bias, C, ldc, M, N, K, epi);
        }
    };
    auto ew = [&](int n) { return dim3((n + 255) / 256); };

    // ---------- embedding ----------
    hipLaunchKernelGGL(temb_kernel, ew(B_ * 384), dim3(256), 0, stream, timestep, temb);
    gemm(temb, D_, time_w, time_b, x + 0 * D_, L_ * D_, B_, D_, D_, 0);
    gemm(text_emb, TXT_, tin_w, tin_b, x + 1 * D_, L_ * D_, B_, D_, TXT_, 0);
    gemm(z_noisy, LAT_, zin_w, zin_b, zfeat, D_, B_ * NP_, D_, LAT_, 0);
    hipLaunchKernelGGL(finalize_embed_kernel, ew(B_ * L_ * D_), dim3(256), 0, stream,
                       x, zfeat, part_emb, tc);

    // ---------- layers ----------
    for (int i = 0; i < NL_; ++i) {
        gemm(x, D_, local_w + (size_t)i * D_ * D_, local_b + (size_t)i * D_,
             cat1, 2 * D_, M_, D_, D_, 1);
        hipLaunchKernelGGL(fill_yrep_kernel, ew(B_ * L_ * D_), dim3(256), 0, stream, cat1, tc);
        gemm(cat1, 2 * D_, f_w + (size_t)i * D_ * 2 * D_, f_b + (size_t)i * D_,
             yhat, D_, M_, D_, 2 * D_, 0);
        hipLaunchKernelGGL(gate_kernel, ew(B_ * L_ * D_), dim3(256), 0, stream, cat1, tc, yhat);
        gemm(cat1, 2 * D_, fuse_w + (size_t)i * D_ * 2 * D_, fuse_b + (size_t)i * D_,
             xt, D_, M_, D_, 2 * D_, 0);

        for (int dir = 0; dir < 2; ++dir) {
            size_t mo = (size_t)(i * 2 + dir);
            gemm(xt, D_, m_in_w + mo * 2 * DI_ * D_, nullptr, xz, 2 * DI_, M_, 2 * DI_, D_, 0);
            hipLaunchKernelGGL(conv_silu_kernel, ew(B_ * L_ * DI_), dim3(256), 0, stream,
                               xz, m_conv_w + mo * DI_ * DC_, m_conv_b + mo * DI_, uc, dir);
            gemm(uc, DI_, m_xproj_w + mo * 80 * DI_, nullptr, xdbl, 80, M_, 80, DI_, 0);
            gemm(xdbl, 80, m_dt_w + mo * DI_ * DTR_, m_dt_b + mo * DI_,
                 dtb, DI_, M_, DI_, DTR_, 2);
            hipLaunchKernelGGL(scan_kernel, dim3(DI_ / 256, B_), dim3(256), 0, stream,
                               dtb, uc, xdbl, xz, m_Alog + mo * DI_ * DS_, m_Dp + mo * DI_,
                               ymam, dir);
            gemm(ymam, DI_, m_out_w + mo * D_ * DI_, nullptr,
                 cat2 + (size_t)dir * D_, 2 * D_, M_, D_, DI_, 0);
        }
        gemm(cat2, 2 * D_, final_w + (size_t)i * D_ * 2 * D_, final_b + (size_t)i * D_,
             xo, D_, M_, D_, 2 * D_, 0);
        hipLaunchKernelGGL(ln_residual_kernel, dim3(M_), dim3(256), 0, stream,
                           xo, x, ln_g + (size_t)i * D_, ln_b + (size_t)i * D_);
    }

    // ---------- output head ----------
    hipLaunchKernelGGL(ln_out_kernel, dim3(B_ * NP_), dim3(256), 0, stream,
                       x, oln_g, oln_b, znorm);
    gemm(znorm, D_, zout_w, zout_b, (float*)d_out, LAT_, B_ * NP_, LAT_, D_, 0);
}

// Round 3
// 2572.313 us; speedup vs baseline: 4.8610x; 1.3330x over previous
//
#include <hip/hip_runtime.h>
#include <hip/hip_bf16.h>
#include <math.h>

// Problem constants
#define B_   256
#define NP_  3
#define LAT_ 512
#define TXT_ 768
#define D_   768
#define NL_  6
#define DI_  1536
#define DS_  16
#define DC_  4
#define DTR_ 48
#define L_   5
#define M_   (B_*L_)
#define EPS_ 1e-5f
#define KSPL 8
#define KC_  192

// ---------------- workspace layout (float offsets), total 52.0 MB ----------------
#define OFF_X     0u          // 983040
#define OFF_TC    983040u     // 196608
#define OFF_TCF   1179648u    // 196608
#define OFF_CAT1  1376256u    // 1966080  (xo, znorm alias)
#define OFF_XT    3342336u    // 983040   (temb alias)
#define OFF_XZ    4325376u    // 3932160
#define OFF_UC    8257536u    // 1966080  (ymam in-place)
#define OFF_XDBLP 10223616u   // 819200   ([8][1280][80])
#define OFF_CAT2  11042816u   // 1966080
// end 13008896 floats = 52.0 MB

typedef __attribute__((ext_vector_type(4))) float floatx4;
typedef __attribute__((ext_vector_type(8))) short short8;
typedef __attribute__((ext_vector_type(4))) unsigned short ushort4v;

__device__ __forceinline__ float sigm(float v) { return 1.f / (1.f + expf(-v)); }
__device__ __forceinline__ float softplus(float v) {
    return fmaxf(v, 0.f) + log1pf(expf(-fabsf(v)));
}

__device__ __forceinline__ unsigned short bf16rn(float f) {
    unsigned int u = __builtin_bit_cast(unsigned int, f);
    u = (u + 0x7fffu + ((u >> 16) & 1u)) >> 16;
    return (unsigned short)u;
}

// ============ MFMA bf16 GEMM: C[m,n] = sum_k A[m,k]*W[n,k] (+bias, +epi) ============
// A: M x K fp32 (lda), W: N x K fp32 (row stride wld), C: M x N fp32 (ldc)
// epi: 0 none, 1 silu, 3 gate: out = aux1[b*768+n] * sigm(acc + aux0[b*768+n]), b=row/5
// SPLITK: blockIdx.z = ks; A/W shifted by ks*kc cols, C shifted ks*M*ldc; K:=kc.
template<int BM, int BN, bool GUARD, bool SPLITK>
__global__ __launch_bounds__(256) void gemm_mfma_kernel(
    const float* __restrict__ A, int lda,
    const float* __restrict__ W, int wld,
    const float* __restrict__ bias,
    const float* __restrict__ aux0,
    const float* __restrict__ aux1,
    float* __restrict__ C, int ldc,
    int M, int N, int K, int epi, int kc)
{
    if constexpr (SPLITK) {
        int ks = blockIdx.z;
        A += (size_t)ks * kc;
        W += (size_t)ks * kc;
        C += (size_t)ks * M * ldc;
        K = kc;
    }
    constexpr int LA = BM / 32;
    constexpr int LB = BN / 32;
    constexpr int FRM = BM / 32;
    constexpr int FRN = BN / 32;

    __shared__ short lds[2][(BM + BN) * 40];

    const int tid = threadIdx.x;
    const int m0 = blockIdx.y * BM, n0 = blockIdx.x * BN;
    const int w = tid >> 6, lane = tid & 63;
    const int wr = w >> 1, wc = w & 1;
    const int lrow = lane & 15;
    const int lk = (lane >> 4) << 3;

    floatx4 ra[LA], rb[LB];
    floatx4 acc[FRM][FRN] = {};

    auto gload = [&](int k0) {
#pragma unroll
        for (int i = 0; i < LA; ++i) {
            int idx = tid + 256 * i; int r = idx >> 3, cb = (idx & 7) * 4;
            if constexpr (GUARD) {
                floatx4 v = {0.f, 0.f, 0.f, 0.f};
                if (m0 + r < M) {
#pragma unroll
                    for (int e = 0; e < 4; ++e)
                        if (k0 + cb + e < K) v[e] = A[(size_t)(m0 + r) * lda + k0 + cb + e];
                }
                ra[i] = v;
            } else {
                ra[i] = *(const floatx4*)(A + (size_t)(m0 + r) * lda + k0 + cb);
            }
        }
#pragma unroll
        for (int i = 0; i < LB; ++i) {
            int idx = tid + 256 * i; int r = idx >> 3, cb = (idx & 7) * 4;
            if constexpr (GUARD) {
                floatx4 v = {0.f, 0.f, 0.f, 0.f};
                if (n0 + r < N) {
#pragma unroll
                    for (int e = 0; e < 4; ++e)
                        if (k0 + cb + e < K) v[e] = W[(size_t)(n0 + r) * wld + k0 + cb + e];
                }
                rb[i] = v;
            } else {
                rb[i] = *(const floatx4*)(W + (size_t)(n0 + r) * wld + k0 + cb);
            }
        }
    };
    auto lstore = [&](int buf) {
        short* pa = lds[buf];
        short* pb = lds[buf] + BM * 40;
#pragma unroll
        for (int i = 0; i < LA; ++i) {
            int idx = tid + 256 * i; int r = idx >> 3, cb = (idx & 7) * 4;
            ushort4v p = { bf16rn(ra[i][0]), bf16rn(ra[i][1]), bf16rn(ra[i][2]), bf16rn(ra[i][3]) };
            *(ushort4v*)(pa + r * 40 + cb) = p;
        }
#pragma unroll
        for (int i = 0; i < LB; ++i) {
            int idx = tid + 256 * i; int r = idx >> 3, cb = (idx & 7) * 4;
            ushort4v p = { bf16rn(rb[i][0]), bf16rn(rb[i][1]), bf16rn(rb[i][2]), bf16rn(rb[i][3]) };
            *(ushort4v*)(pb + r * 40 + cb) = p;
        }
    };

    const int nt = (K + 31) >> 5;
    gload(0);
    lstore(0);
    __syncthreads();
    int cur = 0;
    for (int t = 0; t < nt; ++t) {
        if (t + 1 < nt) gload((t + 1) << 5);
        const short* pa = lds[cur];
        const short* pb = lds[cur] + BM * 40;
        short8 af[FRM], bfv[FRN];
#pragma unroll
        for (int i = 0; i < FRM; ++i)
            af[i] = *(const short8*)(pa + (wr * (BM / 2) + i * 16 + lrow) * 40 + lk);
#pragma unroll
        for (int j = 0; j < FRN; ++j)
            bfv[j] = *(const short8*)(pb + (wc * (BN / 2) + j * 16 + lrow) * 40 + lk);
#pragma unroll
        for (int i = 0; i < FRM; ++i)
#pragma unroll
            for (int j = 0; j < FRN; ++j)
                acc[i][j] = __builtin_amdgcn_mfma_f32_16x16x32_bf16(af[i], bfv[j], acc[i][j], 0, 0, 0);
        if (t + 1 < nt) {
            lstore(cur ^ 1);
            __syncthreads();
            cur ^= 1;
        }
    }

#pragma unroll
    for (int i = 0; i < FRM; ++i) {
        int row0 = m0 + wr * (BM / 2) + i * 16 + (lane >> 4) * 4;
#pragma unroll
        for (int j = 0; j < FRN; ++j) {
            int col = n0 + wc * (BN / 2) + j * 16 + lrow;
            if (GUARD && col >= N) continue;
            float bb = bias ? bias[col] : 0.f;
#pragma unroll
            for (int r = 0; r < 4; ++r) {
                if (GUARD && row0 + r >= M) continue;
                float v = acc[i][j][r] + bb;
                if (epi == 1) {
                    v = v * sigm(v);
                } else if (epi == 3) {
                    int b = (row0 + r) / 5;
                    v = acc[i][j][r] + aux0[(size_t)b * 768 + col];
                    v = aux1[(size_t)b * 768 + col] * sigm(v);
                }
                C[(size_t)(row0 + r) * ldc + col] = v;
            }
        }
    }
}

// ---------------- timestep embedding ----------------
__global__ void temb_kernel(const int* __restrict__ ts, float* __restrict__ temb)
{
    int idx = blockIdx.x * blockDim.x + threadIdx.x;
    if (idx >= B_ * 384) return;
    int j = idx % 384, b = idx / 384;
    float f = expf(-logf(10000.f) * (float)j / 384.f);
    float targ = (float)ts[b] * f;
    temb[(size_t)b * D_ + j]       = cosf(targ);
    temb[(size_t)b * D_ + 384 + j] = sinf(targ);
}

// ---------------- scatter z_feat + part_emb, add PE, save text_cond ----------------
__global__ void finalize_embed_kernel(float* __restrict__ x,
                                      const float* __restrict__ zfeat,
                                      const float* __restrict__ part_emb,
                                      float* __restrict__ tc)
{
    int idx = blockIdx.x * blockDim.x + threadIdx.x;
    if (idx >= B_ * L_ * D_) return;
    int d = idx % D_;
    int bl = idx / D_;
    int l = bl % L_, b = bl / L_;
    float v;
    if (l >= 2) v = zfeat[((size_t)(b * 3 + (l - 2))) * D_ + d] + part_emb[(size_t)(l - 2) * D_ + d];
    else        v = x[idx];
    int j = d >> 1;
    float dv = expf((float)(2 * j) * (-logf(10000.f) / (float)D_));
    float ang = (float)l * dv;
    v += (d & 1) ? cosf(ang) : sinf(ang);
    x[idx] = v;
    if (l == 1) tc[(size_t)b * D_ + d] = v;
}

// ---------------- causal depthwise conv (DC=4) + SiLU ----------------
template<int DIR>
__global__ void conv_silu_kernel(const float* __restrict__ xz,
                                 const float* __restrict__ cw,
                                 const float* __restrict__ cb,
                                 float* __restrict__ uc)
{
    int idx = blockIdx.x * blockDim.x + threadIdx.x;
    if (idx >= B_ * L_ * DI_) return;
    int ch = idx % DI_;
    int bl = idx / DI_;
    int l = bl % L_, b = bl / L_;
    float v = cb[ch];
#pragma unroll
    for (int k = 0; k < DC_; ++k) {
        int lp = DIR ? (l + 3 - k) : (l + k - 3);
        if (lp >= 0 && lp < L_)
            v += cw[(size_t)ch * DC_ + k] * xz[((size_t)(b * L_ + lp)) * (2 * DI_) + ch];
    }
    uc[idx] = v * sigm(v);
}

// ---------------- fused: split-K reduce + dt-proj + softplus + scan + gate ----------
// part: [KSPL][M][80]; uc_ymam: [M][DI] read as uc, overwritten with ymam in place.
template<int DIR>
__global__ __launch_bounds__(256) void dtscan_kernel(
    const float* __restrict__ part,
    float* uc_ymam,
    const float* __restrict__ xz,
    const float* __restrict__ dt_w,
    const float* __restrict__ dt_b,
    const float* __restrict__ Alog,
    const float* __restrict__ Dp)
{
    __shared__ float xd[L_][80];
    const int b = blockIdx.y;
    const int ch = blockIdx.x * 256 + threadIdx.x;

    for (int o = threadIdx.x; o < L_ * 80; o += 256) {
        int l = o / 80, n = o - l * 80;
        float s = 0.f;
#pragma unroll
        for (int ks = 0; ks < KSPL; ++ks)
            s += part[((size_t)ks * M_ + b * L_ + l) * 80 + n];
        xd[l][n] = s;
    }
    __syncthreads();

    // dt projection (rank 48) + softplus
    float dt[L_];
    const float* wp = dt_w + (size_t)ch * DTR_;
    float dbv = dt_b[ch];
#pragma unroll
    for (int l = 0; l < L_; ++l) {
        float v = dbv;
#pragma unroll
        for (int r = 0; r < DTR_; ++r) v = fmaf(xd[l][r], wp[r], v);
        dt[l] = softplus(v);
    }

    float Aa[DS_], h[DS_];
#pragma unroll
    for (int s = 0; s < DS_; ++s) { Aa[s] = -expf(Alog[(size_t)ch * DS_ + s]); h[s] = 0.f; }
    float Dv = Dp[ch];

#pragma unroll
    for (int t = 0; t < L_; ++t) {
        const int l = DIR ? (L_ - 1 - t) : t;
        size_t base = (size_t)(b * L_ + l);
        float dtv = dt[l];
        float ucv = uc_ymam[base * DI_ + ch];
        float du = dtv * ucv;
        float y = 0.f;
#pragma unroll
        for (int s = 0; s < DS_; ++s) {
            h[s] = h[s] * expf(dtv * Aa[s]) + du * xd[l][48 + s];
            y = fmaf(h[s], xd[l][64 + s], y);
        }
        float zv = xz[base * (2 * DI_) + DI_ + ch];
        uc_ymam[base * DI_ + ch] = (y + Dv * ucv) * (zv * sigm(zv));
    }
}

// ---------------- block reduce helper ----------------
__device__ __forceinline__ float block_sum(float v)
{
    __shared__ float sd[4];
#pragma unroll
    for (int o = 1; o < 64; o <<= 1) v += __shfl_xor(v, o, 64);
    int lane = threadIdx.x & 63, wid = threadIdx.x >> 6;
    if (lane == 0) sd[wid] = v;
    __syncthreads();
    v = sd[0] + sd[1] + sd[2] + sd[3];
    __syncthreads();
    return v;
}

__global__ __launch_bounds__(256) void ln_residual_kernel(
    const float* __restrict__ xo, float* __restrict__ x,
    const float* __restrict__ g, const float* __restrict__ bt)
{
    int row = blockIdx.x;
    const float* pa = xo + (size_t)row * D_;
    float* px = x + (size_t)row * D_;
    float v[3];
    float s = 0.f;
#pragma unroll
    for (int i = 0; i < 3; ++i) { int d = threadIdx.x + 256 * i; v[i] = pa[d] + px[d]; s += v[i]; }
    float mean = block_sum(s) * (1.f / (float)D_);
    float sq = 0.f;
#pragma unroll
    for (int i = 0; i < 3; ++i) { float t = v[i] - mean; sq += t * t; }
    float var = block_sum(sq) * (1.f / (float)D_);
    float inv = rsqrtf(var + EPS_);
#pragma unroll
    for (int i = 0; i < 3; ++i) {
        int d = threadIdx.x + 256 * i;
        px[d] = (v[i] - mean) * inv * g[d] + bt[d];
    }
}

__global__ __launch_bounds__(256) void ln_out_kernel(
    const float* __restrict__ x, const float* __restrict__ g,
    const float* __restrict__ bt, float* __restrict__ znorm)
{
    int row = blockIdx.x;
    int b = row / 3, p = row % 3;
    const float* pa = x + ((size_t)(b * L_ + 2 + p)) * D_;
    float* po = znorm + (size_t)row * D_;
    float v[3];
    float s = 0.f;
#pragma unroll
    for (int i = 0; i < 3; ++i) { int d = threadIdx.x + 256 * i; v[i] = pa[d]; s += v[i]; }
    float mean = block_sum(s) * (1.f / (float)D_);
    float sq = 0.f;
#pragma unroll
    for (int i = 0; i < 3; ++i) { float t = v[i] - mean; sq += t * t; }
    float var = block_sum(sq) * (1.f / (float)D_);
    float inv = rsqrtf(var + EPS_);
#pragma unroll
    for (int i = 0; i < 3; ++i) {
        int d = threadIdx.x + 256 * i;
        po[d] = (v[i] - mean) * inv * g[d] + bt[d];
    }
}

extern "C" void kernel_launch(void* const* d_in, const int* in_sizes, int n_in,
                              void* d_out, int out_size, void* d_ws, size_t ws_size,
                              hipStream_t stream)
{
    const float* z_noisy  = (const float*)d_in[0];
    const float* text_emb = (const float*)d_in[1];
    const float* zin_w    = (const float*)d_in[2];
    const float* zin_b    = (const float*)d_in[3];
    const float* tin_w    = (const float*)d_in[4];
    const float* tin_b    = (const float*)d_in[5];
    const float* time_w   = (const float*)d_in[6];
    const float* time_b   = (const float*)d_in[7];
    const float* part_emb = (const float*)d_in[8];
    const float* local_w  = (const float*)d_in[9];
    const float* local_b  = (const float*)d_in[10];
    const float* f_w      = (const float*)d_in[11];
    const float* f_b      = (const float*)d_in[12];
    const float* fuse_w   = (const float*)d_in[13];
    const float* fuse_b   = (const float*)d_in[14];
    const float* final_w  = (const float*)d_in[15];
    const float* final_b  = (const float*)d_in[16];
    const float* ln_g     = (const float*)d_in[17];
    const float* ln_b     = (const float*)d_in[18];
    const float* m_in_w   = (const float*)d_in[19];
    const float* m_conv_w = (const float*)d_in[20];
    const float* m_conv_b = (const float*)d_in[21];
    const float* m_xproj_w= (const float*)d_in[22];
    const float* m_dt_w   = (const float*)d_in[23];
    const float* m_dt_b   = (const float*)d_in[24];
    const float* m_Alog   = (const float*)d_in[25];
    const float* m_Dp     = (const float*)d_in[26];
    const float* m_out_w  = (const float*)d_in[27];
    const float* oln_g    = (const float*)d_in[28];
    const float* oln_b    = (const float*)d_in[29];
    const float* zout_w   = (const float*)d_in[30];
    const float* zout_b   = (const float*)d_in[31];
    const int*   timestep = (const int*)d_in[32];

    float* ws = (float*)d_ws;
    float* x     = ws + OFF_X;
    float* tc    = ws + OFF_TC;
    float* tcf   = ws + OFF_TCF;
    float* cat1  = ws + OFF_CAT1;
    float* xt    = ws + OFF_XT;
    float* xz    = ws + OFF_XZ;
    float* uc    = ws + OFF_UC;      // becomes ymam in place
    float* xdblp = ws + OFF_XDBLP;
    float* cat2  = ws + OFF_CAT2;

    float* zfeat = cat1;
    float* temb  = xt;
    float* xo    = cat1;
    float* znorm = cat1;

    // generic dispatch (non-split)
    auto gemm = [&](const float* A, int lda, const float* W, int wld,
                    const float* bias, const float* a0, const float* a1,
                    float* C, int ldc, int M, int N, int K, int epi) {
        if (N >= 1536 && (N % 128) == 0 && (M % 128) == 0 && (K % 32) == 0) {
            dim3 g(N / 128, M / 128);
            gemm_mfma_kernel<128, 128, false, false><<<g, dim3(256), 0, stream>>>(
                A, lda, W, wld, bias, a0, a1, C, ldc, M, N, K, epi, 0);
        } else if ((N % 64) == 0 && (M % 64) == 0 && (K % 32) == 0) {
            dim3 g(N / 64, M / 64);
            gemm_mfma_kernel<64, 64, false, false><<<g, dim3(256), 0, stream>>>(
                A, lda, W, wld, bias, a0, a1, C, ldc, M, N, K, epi, 0);
        } else {
            dim3 g((N + 63) / 64, (M + 63) / 64);
            gemm_mfma_kernel<64, 64, true, false><<<g, dim3(256), 0, stream>>>(
                A, lda, W, wld, bias, a0, a1, C, ldc, M, N, K, epi, 0);
        }
    };
    auto ew = [&](int n) { return dim3((n + 255) / 256); };

    // ---------- embedding ----------
    hipLaunchKernelGGL(temb_kernel, ew(B_ * 384), dim3(256), 0, stream, timestep, temb);
    gemm(temb, D_, time_w, D_, time_b, nullptr, nullptr, x + 0 * D_, L_ * D_, B_, D_, D_, 0);
    gemm(text_emb, TXT_, tin_w, TXT_, tin_b, nullptr, nullptr, x + 1 * D_, L_ * D_, B_, D_, TXT_, 0);
    gemm(z_noisy, LAT_, zin_w, LAT_, zin_b, nullptr, nullptr, zfeat, D_, B_ * NP_, D_, LAT_, 0);
    hipLaunchKernelGGL(finalize_embed_kernel, ew(B_ * L_ * D_), dim3(256), 0, stream,
                       x, zfeat, part_emb, tc);

    // ---------- layers ----------
    for (int i = 0; i < NL_; ++i) {
        // xl = silu(x @ local^T + b) -> cat1 left
        gemm(x, D_, local_w + (size_t)i * D_ * D_, D_, local_b + (size_t)i * D_,
             nullptr, nullptr, cat1, 2 * D_, M_, D_, D_, 1);
        // tcf = tc @ f_w[:,768:]^T + f_b   (B rows)
        gemm(tc, D_, f_w + (size_t)i * D_ * 2 * D_ + D_, 2 * D_, f_b + (size_t)i * D_,
             nullptr, nullptr, tcf, D_, B_, D_, D_, 0);
        // cat1 right = tc * sigm(xl @ f_w[:,:768]^T + tcf)   (gate fused epilogue)
        gemm(cat1, 2 * D_, f_w + (size_t)i * D_ * 2 * D_, 2 * D_, nullptr,
             tcf, tc, cat1 + D_, 2 * D_, M_, D_, D_, 3);
        // xt = cat1 @ fuse^T + b
        gemm(cat1, 2 * D_, fuse_w + (size_t)i * D_ * 2 * D_, 2 * D_, fuse_b + (size_t)i * D_,
             nullptr, nullptr, xt, D_, M_, D_, 2 * D_, 0);

        for (int dir = 0; dir < 2; ++dir) {
            size_t mo = (size_t)(i * 2 + dir);
            // xz = xt @ in_w^T  (1280 x 3072)
            gemm(xt, D_, m_in_w + mo * 2 * DI_ * D_, D_, nullptr, nullptr, nullptr,
                 xz, 2 * DI_, M_, 2 * DI_, D_, 0);
            // conv + silu -> uc
            if (dir == 0)
                hipLaunchKernelGGL(conv_silu_kernel<0>, ew(B_ * L_ * DI_), dim3(256), 0, stream,
                                   xz, m_conv_w + mo * DI_ * DC_, m_conv_b + mo * DI_, uc);
            else
                hipLaunchKernelGGL(conv_silu_kernel<1>, ew(B_ * L_ * DI_), dim3(256), 0, stream,
                                   xz, m_conv_w + mo * DI_ * DC_, m_conv_b + mo * DI_, uc);
            // split-K xproj partials: grid (2, 20, 8)
            gemm_mfma_kernel<64, 64, true, true><<<dim3(2, M_ / 64, KSPL), dim3(256), 0, stream>>>(
                uc, DI_, m_xproj_w + mo * 80 * DI_, DI_, nullptr, nullptr, nullptr,
                xdblp, 80, M_, 80, DI_, 0, KC_);
            // fused reduce + dt + scan + gate (ymam overwrites uc in place)
            if (dir == 0)
                hipLaunchKernelGGL(dtscan_kernel<0>, dim3(DI_ / 256, B_), dim3(256), 0, stream,
                                   xdblp, uc, xz, m_dt_w + mo * DI_ * DTR_, m_dt_b + mo * DI_,
                                   m_Alog + mo * DI_ * DS_, m_Dp + mo * DI_);
            else
                hipLaunchKernelGGL(dtscan_kernel<1>, dim3(DI_ / 256, B_), dim3(256), 0, stream,
                                   xdblp, uc, xz, m_dt_w + mo * DI_ * DTR_, m_dt_b + mo * DI_,
                                   m_Alog + mo * DI_ * DS_, m_Dp + mo * DI_);
            // out = ymam @ out_w^T -> cat2 col block
            gemm(uc, DI_, m_out_w + mo * D_ * DI_, DI_, nullptr, nullptr, nullptr,
                 cat2 + (size_t)dir * D_, 2 * D_, M_, D_, DI_, 0);
        }
        // xo = cat2 @ final^T + b
        gemm(cat2, 2 * D_, final_w + (size_t)i * D_ * 2 * D_, 2 * D_, final_b + (size_t)i * D_,
             nullptr, nullptr, xo, D_, M_, D_, 2 * D_, 0);
        // x = LN(xo + x)
        hipLaunchKernelGGL(ln_residual_kernel, dim3(M_), dim3(256), 0, stream,
                           xo, x, ln_g + (size_t)i * D_, ln_b + (size_t)i * D_);
    }

    // ---------- output head ----------
    hipLaunchKernelGGL(ln_out_kernel, dim3(B_ * NP_), dim3(256), 0, stream,
                       x, oln_g, oln_b, znorm);
    gemm(znorm, D_, zout_w, D_, zout_b, nullptr, nullptr,
         (float*)d_out, LAT_, B_ * NP_, LAT_, D_, 0);
}

// Round 4
// 1420.808 us; speedup vs baseline: 8.8007x; 1.8105x over previous
//
#include <hip/hip_runtime.h>
#include <hip/hip_bf16.h>
#include <math.h>

// Problem constants
#define B_   256
#define NP_  3
#define LAT_ 512
#define TXT_ 768
#define D_   768
#define NL_  6
#define DI_  1536
#define DS_  16
#define DC_  4
#define DTR_ 48
#define L_   5
#define M_   (B_*L_)
#define EPS_ 1e-5f

// ---------------- workspace layout (BYTE offsets) ----------------
// bf16 arena (weights converted each call; layout order fixed by cvt table)
#define OB_WBF    0ull           // 139,591,680 B = 69,795,840 ush
#define OB_XPP    139591680ull   // xproj padded [12][128][1536] bf16 = 4,718,592
#define OB_TEMB   144310272ull   // [256][768] bf16
#define OB_ZNORM  144703488ull   // [768][768] bf16
#define OB_XBF    145883136ull   // [1280][768] bf16
#define OB_TCBF   147849216ull   // [256][768] bf16
#define OB_CAT1   148242432ull   // [1280][1536] bf16
#define OB_XTBF   152174592ull   // [1280][768] bf16
#define OB_XZBF   154140672ull   // [1280][6144] bf16
#define OB_UCY    169869312ull   // [2][1280][1536] bf16 (uc -> ymam in place)
#define OB_CAT2   177733632ull   // [1280][1536] bf16
// fp32 region
#define OB_X      181665792ull   // [1280][768] f32
#define OB_TC     185597952ull   // [256][768] f32
#define OB_TCF    186384384ull   // [256][768] f32
#define OB_ZFEAT  187170816ull   // [768][768] f32
#define OB_XO     189530112ull   // [1280][768] f32
#define OB_PART   193462272ull   // [16][1280][80] f32 = 6,553,600
// end = 200,015,872 B (~191 MB)

// bf16 weight arena element offsets (cumsum of cvt table)
#define WO_LOCAL  0u
#define WO_F      3538944u
#define WO_FUSE   10616832u
#define WO_FINAL  17694720u
#define WO_IN     24772608u
#define WO_OUT    53084160u
#define WO_ZIN    67239936u
#define WO_TIN    67633152u
#define WO_TIME   68222976u
#define WO_ZOUT   68812800u
#define WO_ZNOISY 69206016u
#define WO_TEXT   69599232u
#define WO_END    69795840u

typedef __attribute__((ext_vector_type(4))) float floatx4;
typedef __attribute__((ext_vector_type(8))) short short8;
typedef __attribute__((ext_vector_type(8))) unsigned short ushort8v;

__device__ __forceinline__ float sigm(float v) { return 1.f / (1.f + expf(-v)); }
__device__ __forceinline__ float softplus(float v) {
    return fmaxf(v, 0.f) + log1pf(expf(-fabsf(v)));
}
__device__ __forceinline__ unsigned short bf16rn(float f) {
    unsigned int u = __builtin_bit_cast(unsigned int, f);
    u = (u + 0x7fffu + ((u >> 16) & 1u)) >> 16;
    return (unsigned short)u;
}
__device__ __forceinline__ float b2f(unsigned short u) {
    unsigned int x = ((unsigned int)u) << 16;
    return __builtin_bit_cast(float, x);
}

// ---------------- bulk fp32 -> bf16 conversion (weights + inputs) ----------------
struct CvtArgs { const float* s[12]; };

__global__ __launch_bounds__(256) void cvt_kernel(CvtArgs a, unsigned short* __restrict__ dst)
{
    constexpr unsigned ends[12] = {
        3538944u, 10616832u, 17694720u, 24772608u, 53084160u, 67239936u,
        67633152u, 68222976u, 68812800u, 69206016u, 69599232u, 69795840u };
    unsigned i8 = (blockIdx.x * 256u + threadIdx.x) * 8u;
    if (i8 >= WO_END) return;
    int t = 0;
    while (i8 >= ends[t]) ++t;
    unsigned start = t ? ends[t - 1] : 0u;
    const float* s = a.s[t] + (i8 - start);
    floatx4 v0 = *(const floatx4*)s;
    floatx4 v1 = *(const floatx4*)(s + 4);
    ushort8v o = { bf16rn(v0[0]), bf16rn(v0[1]), bf16rn(v0[2]), bf16rn(v0[3]),
                   bf16rn(v1[0]), bf16rn(v1[1]), bf16rn(v1[2]), bf16rn(v1[3]) };
    *(ushort8v*)(dst + i8) = o;
}

// xproj pad-convert: [12][80][1536] f32 -> [12][128][1536] bf16 (rows >=80 zero)
__global__ __launch_bounds__(256) void xpad_kernel(const float* __restrict__ xw,
                                                   unsigned short* __restrict__ dst)
{
    unsigned i8 = (blockIdx.x * 256u + threadIdx.x) * 8u;   // over 12*128*1536
    if (i8 >= 12u * 128u * 1536u) return;
    unsigned pi = i8 / (128u * 1536u);
    unsigned rem = i8 - pi * 128u * 1536u;
    unsigned row = rem / 1536u, col = rem - row * 1536u;
    ushort8v o = {0, 0, 0, 0, 0, 0, 0, 0};
    if (row < 80u) {
        const float* s = xw + ((size_t)pi * 80u + row) * 1536u + col;
        floatx4 v0 = *(const floatx4*)s;
        floatx4 v1 = *(const floatx4*)(s + 4);
        o = ushort8v{ bf16rn(v0[0]), bf16rn(v0[1]), bf16rn(v0[2]), bf16rn(v0[3]),
                      bf16rn(v1[0]), bf16rn(v1[1]), bf16rn(v1[2]), bf16rn(v1[3]) };
    }
    *(ushort8v*)(dst + i8) = o;
}

// ============ bf16 MFMA GEMM (m97 structure): C[m,n] = sum_k A[m,k]*W[n,k] ============
// A: M x K bf16 (lda), W: N x K bf16 (wld). C: bf16 (CD=0) or f32 (CD=1).
// epi: 0 none(+bias), 1 silu(+bias), 3 gate: out = aux1[b*768+n]*sigm(acc+aux0[b*768+n])
// blockIdx.z: dir = z/zsplit, ks = z%zsplit. A += dir*zA + ks*K; W += dir*zW + ks*K;
// C += z*zC. All tiles full (no load guards); store guarded by col<ncap.
template<int BM, int BN, int CD>
__global__ __launch_bounds__(256) void gemm_bf16_kernel(
    const unsigned short* __restrict__ A, int lda,
    const unsigned short* __restrict__ W, int wld,
    const float* __restrict__ bias,
    const float* __restrict__ aux0,
    const float* __restrict__ aux1,
    void* __restrict__ Cv, int ldc,
    int M, int N, int K, int epi, int ncap,
    int zsplit, unsigned long long zA, unsigned long long zW, unsigned long long zC)
{
    constexpr int GA = BM / 64;    // global_load_lds instrs for A tile (BM x 32 bf16)
    constexpr int GB = BN / 64;
    constexpr int FRM = BM / 32;
    constexpr int FRN = BN / 32;

    const int z = blockIdx.z;
    const int dirz = z / zsplit, ksz = z - dirz * zsplit;
    A += (unsigned long long)dirz * zA + (unsigned long long)ksz * (unsigned)K;
    W += (unsigned long long)dirz * zW + (unsigned long long)ksz * (unsigned)K;

    __shared__ unsigned short lds[2][(BM + BN) * 32];

    const int tid = threadIdx.x;
    const int m0 = blockIdx.y * BM, n0 = blockIdx.x * BN;
    const int w = tid >> 6, lane = tid & 63;
    const int wr = w >> 1, wc = w & 1;
    const int lrow = lane & 15;
    const int lk = (lane >> 4) << 3;

    floatx4 acc[FRM][FRN] = {};

    auto stage = [&](int buf, int k0) {
        unsigned short* base = &lds[buf][0];
#pragma unroll
        for (int i = 0; i < GA; ++i) {
            int t = tid + i * 256;
            const unsigned short* src = A + (size_t)(m0 + (t >> 2)) * lda + k0 + (t & 3) * 8;
            __builtin_amdgcn_global_load_lds(
                (const __attribute__((address_space(1))) unsigned int*)(const void*)src,
                (__attribute__((address_space(3))) unsigned int*)(void*)(base + i * 2048 + (tid >> 6) * 512),
                16, 0, 0);
        }
#pragma unroll
        for (int i = 0; i < GB; ++i) {
            int t = tid + i * 256;
            const unsigned short* src = W + (size_t)(n0 + (t >> 2)) * wld + k0 + (t & 3) * 8;
            __builtin_amdgcn_global_load_lds(
                (const __attribute__((address_space(1))) unsigned int*)(const void*)src,
                (__attribute__((address_space(3))) unsigned int*)(void*)(base + BM * 32 + i * 2048 + (tid >> 6) * 512),
                16, 0, 0);
        }
    };

    const int nt = K >> 5;
    stage(0, 0);
    __syncthreads();
    int cur = 0;
    for (int t = 0; t < nt; ++t) {
        if (t + 1 < nt) stage(cur ^ 1, (t + 1) << 5);
        const unsigned short* pa = &lds[cur][0];
        const unsigned short* pb = &lds[cur][0] + BM * 32;
        short8 af[FRM], bfv[FRN];
#pragma unroll
        for (int i = 0; i < FRM; ++i)
            af[i] = *(const short8*)(pa + (wr * (BM / 2) + i * 16 + lrow) * 32 + lk);
#pragma unroll
        for (int j = 0; j < FRN; ++j)
            bfv[j] = *(const short8*)(pb + (wc * (BN / 2) + j * 16 + lrow) * 32 + lk);
#pragma unroll
        for (int i = 0; i < FRM; ++i)
#pragma unroll
            for (int j = 0; j < FRN; ++j)
                acc[i][j] = __builtin_amdgcn_mfma_f32_16x16x32_bf16(af[i], bfv[j], acc[i][j], 0, 0, 0);
        __syncthreads();
        cur ^= 1;
    }

#pragma unroll
    for (int i = 0; i < FRM; ++i) {
        int row0 = m0 + wr * (BM / 2) + i * 16 + (lane >> 4) * 4;
#pragma unroll
        for (int j = 0; j < FRN; ++j) {
            int col = n0 + wc * (BN / 2) + j * 16 + lrow;
            if (col >= ncap) continue;
            float bb = bias ? bias[col] : 0.f;
#pragma unroll
            for (int r = 0; r < 4; ++r) {
                int row = row0 + r;
                float v = acc[i][j][r] + bb;
                if (epi == 1) {
                    v = v * sigm(v);
                } else if (epi == 3) {
                    int b = row / 5;
                    v = acc[i][j][r] + aux0[(size_t)b * 768 + col];
                    v = aux1[(size_t)b * 768 + col] * sigm(v);
                }
                size_t off = (size_t)z * zC + (size_t)row * ldc + col;
                if (CD == 1) ((float*)Cv)[off] = v;
                else         ((unsigned short*)Cv)[off] = bf16rn(v);
            }
        }
    }
}

// ---------------- timestep embedding -> bf16 ----------------
__global__ void temb_kernel(const int* __restrict__ ts, unsigned short* __restrict__ temb)
{
    int idx = blockIdx.x * blockDim.x + threadIdx.x;
    if (idx >= B_ * 384) return;
    int j = idx % 384, b = idx / 384;
    float f = expf(-logf(10000.f) * (float)j / 384.f);
    float targ = (float)ts[b] * f;
    temb[(size_t)b * D_ + j]       = bf16rn(cosf(targ));
    temb[(size_t)b * D_ + 384 + j] = bf16rn(sinf(targ));
}

// ---------------- scatter z_feat + part_emb, add PE, write x/x_bf/tc/tc_bf -------
__global__ void finalize_embed_kernel(float* __restrict__ x,
                                      unsigned short* __restrict__ xbf,
                                      const float* __restrict__ zfeat,
                                      const float* __restrict__ part_emb,
                                      float* __restrict__ tc,
                                      unsigned short* __restrict__ tcbf)
{
    int idx = blockIdx.x * blockDim.x + threadIdx.x;
    if (idx >= B_ * L_ * D_) return;
    int d = idx % D_;
    int bl = idx / D_;
    int l = bl % L_, b = bl / L_;
    float v;
    if (l >= 2) v = zfeat[((size_t)(b * 3 + (l - 2))) * D_ + d] + part_emb[(size_t)(l - 2) * D_ + d];
    else        v = x[idx];
    int j = d >> 1;
    float dv = expf((float)(2 * j) * (-logf(10000.f) / (float)D_));
    float ang = (float)l * dv;
    v += (d & 1) ? cosf(ang) : sinf(ang);
    x[idx] = v;
    xbf[idx] = bf16rn(v);
    if (l == 1) { tc[(size_t)b * D_ + d] = v; tcbf[(size_t)b * D_ + d] = bf16rn(v); }
}

// ---------------- causal depthwise conv (both dirs) + SiLU -> ucy bf16 ----------
__global__ void conv_silu_kernel(const unsigned short* __restrict__ xz,
                                 const float* __restrict__ cw,
                                 const float* __restrict__ cb,
                                 unsigned short* __restrict__ ucy)
{
    int idx = blockIdx.x * blockDim.x + threadIdx.x;   // 2*M*DI
    if (idx >= 2 * M_ * DI_) return;
    int ch = idx % DI_;
    int t2 = idx / DI_;
    int bl = t2 % M_, dir = t2 / M_;
    int l = bl % L_, b = bl / L_;
    float v = cb[dir * DI_ + ch];
    const float* wp = cw + ((size_t)(dir * DI_ + ch)) * DC_;
#pragma unroll
    for (int k = 0; k < DC_; ++k) {
        int lp = dir ? (l + 3 - k) : (l + k - 3);
        if (lp >= 0 && lp < L_)
            v += wp[k] * b2f(xz[((size_t)(b * L_ + lp)) * 6144 + dir * 3072 + ch]);
    }
    ucy[idx] = bf16rn(v * sigm(v));
}

// ---------------- fused: split-K reduce + dt-proj + softplus + scan + gate ----------
// part: [16][M][80] (dir slabs of 8); ucy: [2][M][DI] bf16 read uc, write ymam in place
__global__ __launch_bounds__(256) void dtscan_kernel(
    const float* __restrict__ part,
    unsigned short* ucy,
    const unsigned short* __restrict__ xz,
    const float* __restrict__ dt_w,   // [2][DI][48]
    const float* __restrict__ dt_b,   // [2][DI]
    const float* __restrict__ Alog,   // [2][DI][16]
    const float* __restrict__ Dp)     // [2][DI]
{
    __shared__ float xd[L_][80];
    const int dir = blockIdx.z;
    const int b = blockIdx.y;
    const int ch = blockIdx.x * 256 + threadIdx.x;

    for (int o = threadIdx.x; o < L_ * 80; o += 256) {
        int l = o / 80, n = o - l * 80;
        float s = 0.f;
#pragma unroll
        for (int ks = 0; ks < 8; ++ks)
            s += part[((size_t)(dir * 8 + ks) * M_ + b * L_ + l) * 80 + n];
        xd[l][n] = s;
    }
    __syncthreads();

    const int cg = dir * DI_ + ch;
    float dt[L_];
    const float* wp = dt_w + (size_t)cg * DTR_;
    float dbv = dt_b[cg];
#pragma unroll
    for (int l = 0; l < L_; ++l) {
        float v = dbv;
#pragma unroll
        for (int r = 0; r < DTR_; ++r) v = fmaf(xd[l][r], wp[r], v);
        dt[l] = softplus(v);
    }

    float Aa[DS_], h[DS_];
#pragma unroll
    for (int s = 0; s < DS_; ++s) { Aa[s] = -expf(Alog[(size_t)cg * DS_ + s]); h[s] = 0.f; }
    float Dv = Dp[cg];

#pragma unroll
    for (int t = 0; t < L_; ++t) {
        const int l = dir ? (L_ - 1 - t) : t;
        size_t base = (size_t)(b * L_ + l);
        size_t uoff = ((size_t)dir * M_ + base) * DI_ + ch;
        float dtv = dt[l];
        float ucv = b2f(ucy[uoff]);
        float du = dtv * ucv;
        float y = 0.f;
#pragma unroll
        for (int s = 0; s < DS_; ++s) {
            h[s] = h[s] * expf(dtv * Aa[s]) + du * xd[l][48 + s];
            y = fmaf(h[s], xd[l][64 + s], y);
        }
        float zv = b2f(xz[base * 6144 + dir * 3072 + 1536 + ch]);
        ucy[uoff] = bf16rn((y + Dv * ucv) * (zv * sigm(zv)));
    }
}

// ---------------- block reduce helper ----------------
__device__ __forceinline__ float block_sum(float v)
{
    __shared__ float sd[4];
#pragma unroll
    for (int o = 1; o < 64; o <<= 1) v += __shfl_xor(v, o, 64);
    int lane = threadIdx.x & 63, wid = threadIdx.x >> 6;
    if (lane == 0) sd[wid] = v;
    __syncthreads();
    v = sd[0] + sd[1] + sd[2] + sd[3];
    __syncthreads();
    return v;
}

__global__ __launch_bounds__(256) void ln_residual_kernel(
    const float* __restrict__ xo, float* __restrict__ x,
    unsigned short* __restrict__ xbf,
    const float* __restrict__ g, const float* __restrict__ bt)
{
    int row = blockIdx.x;
    const float* pa = xo + (size_t)row * D_;
    float* px = x + (size_t)row * D_;
    float v[3];
    float s = 0.f;
#pragma unroll
    for (int i = 0; i < 3; ++i) { int d = threadIdx.x + 256 * i; v[i] = pa[d] + px[d]; s += v[i]; }
    float mean = block_sum(s) * (1.f / (float)D_);
    float sq = 0.f;
#pragma unroll
    for (int i = 0; i < 3; ++i) { float t = v[i] - mean; sq += t * t; }
    float var = block_sum(sq) * (1.f / (float)D_);
    float inv = rsqrtf(var + EPS_);
#pragma unroll
    for (int i = 0; i < 3; ++i) {
        int d = threadIdx.x + 256 * i;
        float o = (v[i] - mean) * inv * g[d] + bt[d];
        px[d] = o;
        xbf[(size_t)row * D_ + d] = bf16rn(o);
    }
}

__global__ __launch_bounds__(256) void ln_out_kernel(
    const float* __restrict__ x, const float* __restrict__ g,
    const float* __restrict__ bt, unsigned short* __restrict__ znorm)
{
    int row = blockIdx.x;
    int b = row / 3, p = row % 3;
    const float* pa = x + ((size_t)(b * L_ + 2 + p)) * D_;
    float v[3];
    float s = 0.f;
#pragma unroll
    for (int i = 0; i < 3; ++i) { int d = threadIdx.x + 256 * i; v[i] = pa[d]; s += v[i]; }
    float mean = block_sum(s) * (1.f / (float)D_);
    float sq = 0.f;
#pragma unroll
    for (int i = 0; i < 3; ++i) { float t = v[i] - mean; sq += t * t; }
    float var = block_sum(sq) * (1.f / (float)D_);
    float inv = rsqrtf(var + EPS_);
#pragma unroll
    for (int i = 0; i < 3; ++i) {
        int d = threadIdx.x + 256 * i;
        znorm[(size_t)row * D_ + d] = bf16rn((v[i] - mean) * inv * g[d] + bt[d]);
    }
}

extern "C" void kernel_launch(void* const* d_in, const int* in_sizes, int n_in,
                              void* d_out, int out_size, void* d_ws, size_t ws_size,
                              hipStream_t stream)
{
    const float* z_noisy  = (const float*)d_in[0];
    const float* text_emb = (const float*)d_in[1];
    const float* zin_b    = (const float*)d_in[3];
    const float* tin_b    = (const float*)d_in[5];
    const float* time_b   = (const float*)d_in[7];
    const float* part_emb = (const float*)d_in[8];
    const float* local_b  = (const float*)d_in[10];
    const float* f_b      = (const float*)d_in[12];
    const float* fuse_b   = (const float*)d_in[14];
    const float* final_b  = (const float*)d_in[16];
    const float* ln_g     = (const float*)d_in[17];
    const float* ln_b     = (const float*)d_in[18];
    const float* m_conv_w = (const float*)d_in[20];
    const float* m_conv_b = (const float*)d_in[21];
    const float* m_xproj_w= (const float*)d_in[22];
    const float* m_dt_w   = (const float*)d_in[23];
    const float* m_dt_b   = (const float*)d_in[24];
    const float* m_Alog   = (const float*)d_in[25];
    const float* m_Dp     = (const float*)d_in[26];
    const float* oln_g    = (const float*)d_in[28];
    const float* oln_b    = (const float*)d_in[29];
    const float* zout_b   = (const float*)d_in[31];
    const int*   timestep = (const int*)d_in[32];

    char* wsb = (char*)d_ws;
    unsigned short* wbf   = (unsigned short*)(wsb + OB_WBF);
    unsigned short* xpp   = (unsigned short*)(wsb + OB_XPP);
    unsigned short* tembb = (unsigned short*)(wsb + OB_TEMB);
    unsigned short* znormb= (unsigned short*)(wsb + OB_ZNORM);
    unsigned short* xbf   = (unsigned short*)(wsb + OB_XBF);
    unsigned short* tcbf  = (unsigned short*)(wsb + OB_TCBF);
    unsigned short* cat1b = (unsigned short*)(wsb + OB_CAT1);
    unsigned short* xtbf  = (unsigned short*)(wsb + OB_XTBF);
    unsigned short* xzbf  = (unsigned short*)(wsb + OB_XZBF);
    unsigned short* ucy   = (unsigned short*)(wsb + OB_UCY);
    unsigned short* cat2b = (unsigned short*)(wsb + OB_CAT2);
    float* x     = (float*)(wsb + OB_X);
    float* tc    = (float*)(wsb + OB_TC);
    float* tcf   = (float*)(wsb + OB_TCF);
    float* zfeat = (float*)(wsb + OB_ZFEAT);
    float* xo    = (float*)(wsb + OB_XO);
    float* part  = (float*)(wsb + OB_PART);

    // weight views in bf16 arena
    unsigned short* local_bf = wbf + WO_LOCAL;
    unsigned short* f_bf     = wbf + WO_F;
    unsigned short* fuse_bf  = wbf + WO_FUSE;
    unsigned short* final_bf = wbf + WO_FINAL;
    unsigned short* in_bf    = wbf + WO_IN;
    unsigned short* out_bf   = wbf + WO_OUT;
    unsigned short* zin_bf   = wbf + WO_ZIN;
    unsigned short* tin_bf   = wbf + WO_TIN;
    unsigned short* time_bf  = wbf + WO_TIME;
    unsigned short* zout_bf  = wbf + WO_ZOUT;
    unsigned short* znz_bf   = wbf + WO_ZNOISY;
    unsigned short* text_bf  = wbf + WO_TEXT;

    auto ew = [&](int n) { return dim3((n + 255) / 256); };

    // ---------- conversion pass ----------
    CvtArgs ca;
    ca.s[0] = (const float*)d_in[9];   // local_w
    ca.s[1] = (const float*)d_in[11];  // f_w
    ca.s[2] = (const float*)d_in[13];  // fuse_w
    ca.s[3] = (const float*)d_in[15];  // final_w
    ca.s[4] = (const float*)d_in[19];  // m_in_w
    ca.s[5] = (const float*)d_in[27];  // m_out_w
    ca.s[6] = (const float*)d_in[2];   // zin_w
    ca.s[7] = (const float*)d_in[4];   // tin_w
    ca.s[8] = (const float*)d_in[6];   // time_w
    ca.s[9] = (const float*)d_in[30];  // zout_w
    ca.s[10] = z_noisy;
    ca.s[11] = text_emb;
    hipLaunchKernelGGL(cvt_kernel, dim3(WO_END / 8 / 256), dim3(256), 0, stream, ca, wbf);
    hipLaunchKernelGGL(xpad_kernel, dim3(12 * 128 * 1536 / 8 / 256), dim3(256), 0, stream,
                       m_xproj_w, xpp);
    hipLaunchKernelGGL(temb_kernel, ew(B_ * 384), dim3(256), 0, stream, timestep, tembb);

    // GEMM launchers
    auto g64 = [&](const unsigned short* A, int lda, const unsigned short* W, int wld,
                   const float* bias, const float* a0, const float* a1,
                   void* C, int ldc, int Mm, int Nn, int Kk, int epi, int ncap, int cd,
                   int gz, int zsplit, unsigned long long zA, unsigned long long zW,
                   unsigned long long zC) {
        dim3 g(Nn / 64, Mm / 64, gz);
        if (cd == 1)
            gemm_bf16_kernel<64, 64, 1><<<g, dim3(256), 0, stream>>>(
                A, lda, W, wld, bias, a0, a1, C, ldc, Mm, Nn, Kk, epi, ncap, zsplit, zA, zW, zC);
        else
            gemm_bf16_kernel<64, 64, 0><<<g, dim3(256), 0, stream>>>(
                A, lda, W, wld, bias, a0, a1, C, ldc, Mm, Nn, Kk, epi, ncap, zsplit, zA, zW, zC);
    };

    // ---------- embedding ----------
    g64(tembb, D_, time_bf, D_, time_b, nullptr, nullptr, x, L_ * D_, B_, D_, D_, 0, D_, 1,
        1, 1, 0, 0, 0);
    g64(text_bf, TXT_, tin_bf, TXT_, tin_b, nullptr, nullptr, x + D_, L_ * D_, B_, D_, TXT_, 0, D_, 1,
        1, 1, 0, 0, 0);
    g64(znz_bf, LAT_, zin_bf, LAT_, zin_b, nullptr, nullptr, zfeat, D_, B_ * NP_, D_, LAT_, 0, D_, 1,
        1, 1, 0, 0, 0);
    hipLaunchKernelGGL(finalize_embed_kernel, ew(B_ * L_ * D_), dim3(256), 0, stream,
                       x, xbf, zfeat, part_emb, tc, tcbf);

    // ---------- layers ----------
    for (int i = 0; i < NL_; ++i) {
        // xl = silu(x @ local^T + b) -> cat1 left (bf16)
        g64(xbf, D_, local_bf + (size_t)i * D_ * D_, D_, local_b + (size_t)i * D_,
            nullptr, nullptr, cat1b, 2 * D_, M_, D_, D_, 1, D_, 0, 1, 1, 0, 0, 0);
        // tcf = tc @ f_w[:,768:]^T + f_b  (f32, B rows)
        g64(tcbf, D_, f_bf + (size_t)i * D_ * 2 * D_ + D_, 2 * D_, f_b + (size_t)i * D_,
            nullptr, nullptr, tcf, D_, B_, D_, D_, 0, D_, 1, 1, 1, 0, 0, 0);
        // cat1 right = tc * sigm(xl @ f_w[:,:768]^T + tcf)
        g64(cat1b, 2 * D_, f_bf + (size_t)i * D_ * 2 * D_, 2 * D_, nullptr,
            tcf, tc, cat1b + D_, 2 * D_, M_, D_, D_, 3, D_, 0, 1, 1, 0, 0, 0);
        // xt = cat1 @ fuse^T + b (bf16)
        g64(cat1b, 2 * D_, fuse_bf + (size_t)i * D_ * 2 * D_, 2 * D_, fuse_b + (size_t)i * D_,
            nullptr, nullptr, xtbf, D_, M_, D_, 2 * D_, 0, D_, 0, 1, 1, 0, 0, 0);

        // xz = xt @ [in_w0; in_w1]^T  (1280 x 6144, bf16) -- 64x128 tile
        {
            dim3 g(6144 / 128, M_ / 64, 1);
            gemm_bf16_kernel<64, 128, 0><<<g, dim3(256), 0, stream>>>(
                xtbf, D_, in_bf + (size_t)i * 2 * 2 * DI_ * D_ / 2, D_, nullptr, nullptr, nullptr,
                xzbf, 2 * 2 * DI_ / 2, M_, 6144, D_, 0, 6144, 1, 0, 0, 0);
        }
        // conv + silu (both dirs) -> ucy bf16
        hipLaunchKernelGGL(conv_silu_kernel, ew(2 * M_ * DI_), dim3(256), 0, stream,
                           xzbf, m_conv_w + (size_t)i * 2 * DI_ * DC_,
                           m_conv_b + (size_t)i * 2 * DI_, ucy);
        // xproj split-K partials: grid (2, 20, 16); z = dir*8 + ks; K chunk 192
        {
            dim3 g(128 / 64, M_ / 64, 16);
            gemm_bf16_kernel<64, 64, 1><<<g, dim3(256), 0, stream>>>(
                ucy, DI_, xpp + (size_t)i * 2 * 128 * DI_, DI_, nullptr, nullptr, nullptr,
                part, 80, M_, 128, 192, 0, 80,
                8, (unsigned long long)M_ * DI_, (unsigned long long)128 * DI_,
                (unsigned long long)M_ * 80);
        }
        // fused reduce + dt + scan + gate (ymam overwrites ucy in place)
        hipLaunchKernelGGL(dtscan_kernel, dim3(DI_ / 256, B_, 2), dim3(256), 0, stream,
                           part, ucy, xzbf,
                           m_dt_w + (size_t)i * 2 * DI_ * DTR_, m_dt_b + (size_t)i * 2 * DI_,
                           m_Alog + (size_t)i * 2 * DI_ * DS_, m_Dp + (size_t)i * 2 * DI_);
        // out = ymam @ out_w^T -> cat2 (both dirs via z)
        g64(ucy, DI_, out_bf + (size_t)i * 2 * D_ * DI_, DI_, nullptr, nullptr, nullptr,
            cat2b, 2 * D_, M_, D_, DI_, 0, D_, 0,
            2, 1, (unsigned long long)M_ * DI_, (unsigned long long)D_ * DI_, 768ull);
        // xo = cat2 @ final^T + b (f32)
        g64(cat2b, 2 * D_, final_bf + (size_t)i * D_ * 2 * D_, 2 * D_, final_b + (size_t)i * D_,
            nullptr, nullptr, xo, D_, M_, D_, 2 * D_, 0, D_, 1, 1, 1, 0, 0, 0);
        // x = LN(xo + x), also write xbf
        hipLaunchKernelGGL(ln_residual_kernel, dim3(M_), dim3(256), 0, stream,
                           xo, x, xbf, ln_g + (size_t)i * D_, ln_b + (size_t)i * D_);
    }

    // ---------- output head ----------
    hipLaunchKernelGGL(ln_out_kernel, dim3(B_ * NP_), dim3(256), 0, stream,
                       x, oln_g, oln_b, znormb);
    g64(znormb, D_, zout_bf, D_, zout_b, nullptr, nullptr,
        (float*)d_out, LAT_, B_ * NP_, LAT_, D_, 0, LAT_, 1, 1, 1, 0, 0, 0);
}

// Round 5
// 1232.200 us; speedup vs baseline: 10.1478x; 1.1531x over previous
//
#include <hip/hip_runtime.h>
#include <hip/hip_bf16.h>
#include <math.h>

// Problem constants
#define B_   256
#define NP_  3
#define LAT_ 512
#define TXT_ 768
#define D_   768
#define NL_  6
#define DI_  1536
#define DS_  16
#define DC_  4
#define DTR_ 48
#define L_   5
#define M_   (B_*L_)
#define EPS_ 1e-5f

// ---------------- workspace layout (BYTE offsets) ----------------
#define OB_WBF    0ull           // 139,591,680 B = 69,795,840 ush
#define OB_XPP    139591680ull   // xproj padded [12][128][1536] bf16
#define OB_TEMB   144310272ull   // [256][768] bf16
#define OB_ZNORM  144703488ull   // [768][768] bf16
#define OB_XBF    145883136ull   // [1280][768] bf16
#define OB_TCBF   147849216ull   // [256][768] bf16
#define OB_CAT1   148242432ull   // [1280][1536] bf16
#define OB_XTBF   152174592ull   // [1280][768] bf16
#define OB_XZBF   154140672ull   // [1280][6144] bf16
#define OB_UCY    169869312ull   // [2][1280][1536] bf16 (uc -> ymam in place)
#define OB_CAT2   177733632ull   // [1280][1536] bf16
#define OB_X      181665792ull   // [1280][768] f32
#define OB_TC     185597952ull   // [256][768] f32
#define OB_TCF    186384384ull   // [256][768] f32
#define OB_ZFEAT  187170816ull   // [768][768] f32
#define OB_XO     189530112ull   // [1280][768] f32
#define OB_PART   193462272ull   // [16][1280][80] f32

// bf16 weight arena element offsets
#define WO_LOCAL  0u
#define WO_F      3538944u
#define WO_FUSE   10616832u
#define WO_FINAL  17694720u
#define WO_IN     24772608u
#define WO_OUT    53084160u
#define WO_ZIN    67239936u
#define WO_TIN    67633152u
#define WO_TIME   68222976u
#define WO_ZOUT   68812800u
#define WO_ZNOISY 69206016u
#define WO_TEXT   69599232u
#define WO_END    69795840u

typedef __attribute__((ext_vector_type(4))) float floatx4;
typedef __attribute__((ext_vector_type(8))) short short8;
typedef __attribute__((ext_vector_type(8))) unsigned short ushort8v;

__device__ __forceinline__ float sigm(float v) { return 1.f / (1.f + expf(-v)); }
__device__ __forceinline__ float softplus(float v) {
    return fmaxf(v, 0.f) + log1pf(expf(-fabsf(v)));
}
__device__ __forceinline__ unsigned short bf16rn(float f) {
    unsigned int u = __builtin_bit_cast(unsigned int, f);
    u = (u + 0x7fffu + ((u >> 16) & 1u)) >> 16;
    return (unsigned short)u;
}
__device__ __forceinline__ float b2f(unsigned short u) {
    unsigned int x = ((unsigned int)u) << 16;
    return __builtin_bit_cast(float, x);
}

template<int N> __device__ __forceinline__ void wait_vmcnt() {
    if constexpr (N == 0) asm volatile("s_waitcnt vmcnt(0)" ::: "memory");
    else if constexpr (N == 2) asm volatile("s_waitcnt vmcnt(2)" ::: "memory");
    else if constexpr (N == 3) asm volatile("s_waitcnt vmcnt(3)" ::: "memory");
    else if constexpr (N == 4) asm volatile("s_waitcnt vmcnt(4)" ::: "memory");
    else if constexpr (N == 6) asm volatile("s_waitcnt vmcnt(6)" ::: "memory");
}

// ---------------- bulk fp32 -> bf16 conversion (16 elems/thread) ----------------
struct CvtArgs { const float* s[12]; };

__global__ __launch_bounds__(256) void cvt_kernel(CvtArgs a, unsigned short* __restrict__ dst)
{
    constexpr unsigned ends[12] = {
        3538944u, 10616832u, 17694720u, 24772608u, 53084160u, 67239936u,
        67633152u, 68222976u, 68812800u, 69206016u, 69599232u, 69795840u };
    unsigned i16 = (blockIdx.x * 256u + threadIdx.x) * 16u;
    if (i16 >= WO_END) return;
    int t = 0;
    while (i16 >= ends[t]) ++t;
    unsigned start = t ? ends[t - 1] : 0u;
    const float* s = a.s[t] + (i16 - start);
    floatx4 v0 = *(const floatx4*)s;
    floatx4 v1 = *(const floatx4*)(s + 4);
    floatx4 v2 = *(const floatx4*)(s + 8);
    floatx4 v3 = *(const floatx4*)(s + 12);
    ushort8v o0 = { bf16rn(v0[0]), bf16rn(v0[1]), bf16rn(v0[2]), bf16rn(v0[3]),
                    bf16rn(v1[0]), bf16rn(v1[1]), bf16rn(v1[2]), bf16rn(v1[3]) };
    ushort8v o1 = { bf16rn(v2[0]), bf16rn(v2[1]), bf16rn(v2[2]), bf16rn(v2[3]),
                    bf16rn(v3[0]), bf16rn(v3[1]), bf16rn(v3[2]), bf16rn(v3[3]) };
    *(ushort8v*)(dst + i16) = o0;
    *(ushort8v*)(dst + i16 + 8) = o1;
}

// xproj pad-convert: [12][80][1536] f32 -> [12][128][1536] bf16 (rows >=80 zero)
__global__ __launch_bounds__(256) void xpad_kernel(const float* __restrict__ xw,
                                                   unsigned short* __restrict__ dst)
{
    unsigned i8 = (blockIdx.x * 256u + threadIdx.x) * 8u;
    if (i8 >= 12u * 128u * 1536u) return;
    unsigned pi = i8 / (128u * 1536u);
    unsigned rem = i8 - pi * 128u * 1536u;
    unsigned row = rem / 1536u, col = rem - row * 1536u;
    ushort8v o = {0, 0, 0, 0, 0, 0, 0, 0};
    if (row < 80u) {
        const float* s = xw + ((size_t)pi * 80u + row) * 1536u + col;
        floatx4 v0 = *(const floatx4*)s;
        floatx4 v1 = *(const floatx4*)(s + 4);
        o = ushort8v{ bf16rn(v0[0]), bf16rn(v0[1]), bf16rn(v0[2]), bf16rn(v0[3]),
                      bf16rn(v1[0]), bf16rn(v1[1]), bf16rn(v1[2]), bf16rn(v1[3]) };
    }
    *(ushort8v*)(dst + i8) = o;
}

// ============ bf16 MFMA GEMM, 4-deep pipeline + counted vmcnt + LDS swizzle ============
// A: M x K bf16 (lda), W: N x K bf16 (wld). C: bf16 (CD=0) or f32 (CD=1).
// epi: 0 none(+bias), 1 silu(+bias), 3 gate: out = aux1[b*768+n]*sigm(acc+aux0[b*768+n])
// blockIdx.z: dirz = z/zsplit, ksz = z%zsplit. A += dirz*zA + ksz*K; W += dirz*zW + ksz*K;
// C += z*zC. Tiles always full (no load guards); store guarded by col<ncap.
// LDS layout: rows of 32 bf16 (64B); 16B slot s of row r holds global k-slot s^((r>>1)&3).
template<int BM, int BN, int CD>
__global__ __launch_bounds__(256) void gemm_bf16_kernel(
    const unsigned short* __restrict__ A, int lda,
    const unsigned short* __restrict__ W, int wld,
    const float* __restrict__ bias,
    const float* __restrict__ aux0,
    const float* __restrict__ aux1,
    void* __restrict__ Cv, int ldc,
    int M, int N, int K, int epi, int ncap,
    int zsplit, unsigned long long zA, unsigned long long zW, unsigned long long zC)
{
    constexpr int GA = BM / 64;       // global_load_lds instrs per stage for A
    constexpr int GB = BN / 64;
    constexpr int LPS = GA + GB;      // per-wave loads per stage
    constexpr int FRM = BM / 32;
    constexpr int FRN = BN / 32;

    const int z = blockIdx.z;
    const int dirz = z / zsplit, ksz = z - dirz * zsplit;
    A += (unsigned long long)dirz * zA + (unsigned long long)ksz * (unsigned)K;
    W += (unsigned long long)dirz * zW + (unsigned long long)ksz * (unsigned)K;

    __shared__ unsigned short lds[4][(BM + BN) * 32];

    const int tid = threadIdx.x;
    const int m0 = blockIdx.y * BM, n0 = blockIdx.x * BN;
    const int w = tid >> 6, lane = tid & 63;
    const int wr = w >> 1, wc = w & 1;
    const int lrow = lane & 15;
    const int lk = (lane >> 4) << 3;

    // pre-swizzled global source column offsets (elements)
    const int rA = tid >> 2, sA = tid & 3;
    const int scA = ((sA ^ ((rA >> 1) & 3)) << 3);
    floatx4 acc[FRM][FRN] = {};

    auto stage = [&](int buf, int k0) {
        unsigned short* base = &lds[buf][0];
#pragma unroll
        for (int i = 0; i < GA; ++i) {
            int t = tid + i * 256;
            int r = t >> 2;
            const unsigned short* src = A + (size_t)(m0 + r) * lda + k0 + scA;
            __builtin_amdgcn_global_load_lds(
                (const __attribute__((address_space(1))) unsigned int*)(const void*)src,
                (__attribute__((address_space(3))) unsigned int*)(void*)(base + i * 2048 + w * 512),
                16, 0, 0);
        }
#pragma unroll
        for (int i = 0; i < GB; ++i) {
            int t = tid + i * 256;
            int r = t >> 2;
            const unsigned short* src = W + (size_t)(n0 + r) * wld + k0 + scA;
            __builtin_amdgcn_global_load_lds(
                (const __attribute__((address_space(1))) unsigned int*)(const void*)src,
                (__attribute__((address_space(3))) unsigned int*)(void*)(base + BM * 32 + i * 2048 + w * 512),
                16, 0, 0);
        }
    };

    const int nt = K >> 5;
    stage(0, 0);
    if (nt > 1) stage(1, 32);

    // precompute swizzled fragment element offsets
    int offA[FRM], offB[FRN];
#pragma unroll
    for (int i = 0; i < FRM; ++i) {
        int row = wr * (BM / 2) + i * 16 + lrow;
        offA[i] = row * 32 + (lk ^ (((row >> 1) & 3) << 3));
    }
#pragma unroll
    for (int j = 0; j < FRN; ++j) {
        int row = wc * (BN / 2) + j * 16 + lrow;
        offB[j] = BM * 32 + row * 32 + (lk ^ (((row >> 1) & 3) << 3));
    }

    for (int t = 0; t < nt; ++t) {
        if (t + 2 < nt) {
            stage((t + 2) & 3, (t + 2) << 5);
            wait_vmcnt<2 * LPS>();
        } else if (t + 1 < nt) {
            wait_vmcnt<LPS>();
        } else {
            wait_vmcnt<0>();
        }
        __builtin_amdgcn_s_barrier();
        const unsigned short* pl = &lds[t & 3][0];
        short8 af[FRM], bfv[FRN];
#pragma unroll
        for (int i = 0; i < FRM; ++i) af[i] = *(const short8*)(pl + offA[i]);
#pragma unroll
        for (int j = 0; j < FRN; ++j) bfv[j] = *(const short8*)(pl + offB[j]);
#pragma unroll
        for (int i = 0; i < FRM; ++i)
#pragma unroll
            for (int j = 0; j < FRN; ++j)
                acc[i][j] = __builtin_amdgcn_mfma_f32_16x16x32_bf16(af[i], bfv[j], acc[i][j], 0, 0, 0);
    }

#pragma unroll
    for (int i = 0; i < FRM; ++i) {
        int row0 = m0 + wr * (BM / 2) + i * 16 + (lane >> 4) * 4;
#pragma unroll
        for (int j = 0; j < FRN; ++j) {
            int col = n0 + wc * (BN / 2) + j * 16 + lrow;
            if (col >= ncap) continue;
            float bb = bias ? bias[col] : 0.f;
#pragma unroll
            for (int r = 0; r < 4; ++r) {
                int row = row0 + r;
                float v = acc[i][j][r] + bb;
                if (epi == 1) {
                    v = v * sigm(v);
                } else if (epi == 3) {
                    int b = row / 5;
                    v = acc[i][j][r] + aux0[(size_t)b * 768 + col];
                    v = aux1[(size_t)b * 768 + col] * sigm(v);
                }
                size_t off = (size_t)z * zC + (size_t)row * ldc + col;
                if (CD == 1) ((float*)Cv)[off] = v;
                else         ((unsigned short*)Cv)[off] = bf16rn(v);
            }
        }
    }
}

// ---------------- timestep embedding -> bf16 ----------------
__global__ void temb_kernel(const int* __restrict__ ts, unsigned short* __restrict__ temb)
{
    int idx = blockIdx.x * blockDim.x + threadIdx.x;
    if (idx >= B_ * 384) return;
    int j = idx % 384, b = idx / 384;
    float f = expf(-logf(10000.f) * (float)j / 384.f);
    float targ = (float)ts[b] * f;
    temb[(size_t)b * D_ + j]       = bf16rn(cosf(targ));
    temb[(size_t)b * D_ + 384 + j] = bf16rn(sinf(targ));
}

// ---------------- scatter z_feat + part_emb, add PE, write x/x_bf/tc/tc_bf -------
__global__ void finalize_embed_kernel(float* __restrict__ x,
                                      unsigned short* __restrict__ xbf,
                                      const float* __restrict__ zfeat,
                                      const float* __restrict__ part_emb,
                                      float* __restrict__ tc,
                                      unsigned short* __restrict__ tcbf)
{
    int idx = blockIdx.x * blockDim.x + threadIdx.x;
    if (idx >= B_ * L_ * D_) return;
    int d = idx % D_;
    int bl = idx / D_;
    int l = bl % L_, b = bl / L_;
    float v;
    if (l >= 2) v = zfeat[((size_t)(b * 3 + (l - 2))) * D_ + d] + part_emb[(size_t)(l - 2) * D_ + d];
    else        v = x[idx];
    int j = d >> 1;
    float dv = expf((float)(2 * j) * (-logf(10000.f) / (float)D_));
    float ang = (float)l * dv;
    v += (d & 1) ? cosf(ang) : sinf(ang);
    x[idx] = v;
    xbf[idx] = bf16rn(v);
    if (l == 1) { tc[(size_t)b * D_ + d] = v; tcbf[(size_t)b * D_ + d] = bf16rn(v); }
}

// ---------------- causal depthwise conv (both dirs) + SiLU -> ucy bf16 ----------
__global__ void conv_silu_kernel(const unsigned short* __restrict__ xz,
                                 const float* __restrict__ cw,
                                 const float* __restrict__ cb,
                                 unsigned short* __restrict__ ucy)
{
    int idx = blockIdx.x * blockDim.x + threadIdx.x;   // 2*M*DI
    if (idx >= 2 * M_ * DI_) return;
    int ch = idx % DI_;
    int t2 = idx / DI_;
    int bl = t2 % M_, dir = t2 / M_;
    int l = bl % L_, b = bl / L_;
    float v = cb[dir * DI_ + ch];
    const float* wp = cw + ((size_t)(dir * DI_ + ch)) * DC_;
#pragma unroll
    for (int k = 0; k < DC_; ++k) {
        int lp = dir ? (l + 3 - k) : (l + k - 3);
        if (lp >= 0 && lp < L_)
            v += wp[k] * b2f(xz[((size_t)(b * L_ + lp)) * 6144 + dir * 3072 + ch]);
    }
    ucy[idx] = bf16rn(v * sigm(v));
}

// ---------------- fused: split-K reduce + dt-proj + softplus + scan + gate ----------
__global__ __launch_bounds__(256) void dtscan_kernel(
    const float* __restrict__ part,
    unsigned short* ucy,
    const unsigned short* __restrict__ xz,
    const float* __restrict__ dt_w,
    const float* __restrict__ dt_b,
    const float* __restrict__ Alog,
    const float* __restrict__ Dp)
{
    __shared__ float xd[L_][80];
    const int dir = blockIdx.z;
    const int b = blockIdx.y;
    const int ch = blockIdx.x * 256 + threadIdx.x;

    for (int o = threadIdx.x; o < L_ * 80; o += 256) {
        int l = o / 80, n = o - l * 80;
        float s = 0.f;
#pragma unroll
        for (int ks = 0; ks < 8; ++ks)
            s += part[((size_t)(dir * 8 + ks) * M_ + b * L_ + l) * 80 + n];
        xd[l][n] = s;
    }
    __syncthreads();

    const int cg = dir * DI_ + ch;
    float dt[L_];
    const float* wp = dt_w + (size_t)cg * DTR_;
    float dbv = dt_b[cg];
#pragma unroll
    for (int l = 0; l < L_; ++l) {
        float v = dbv;
#pragma unroll
        for (int r = 0; r < DTR_; ++r) v = fmaf(xd[l][r], wp[r], v);
        dt[l] = softplus(v);
    }

    float Aa[DS_], h[DS_];
#pragma unroll
    for (int s = 0; s < DS_; ++s) { Aa[s] = -expf(Alog[(size_t)cg * DS_ + s]); h[s] = 0.f; }
    float Dv = Dp[cg];

#pragma unroll
    for (int t = 0; t < L_; ++t) {
        const int l = dir ? (L_ - 1 - t) : t;
        size_t base = (size_t)(b * L_ + l);
        size_t uoff = ((size_t)dir * M_ + base) * DI_ + ch;
        float dtv = dt[l];
        float ucv = b2f(ucy[uoff]);
        float du = dtv * ucv;
        float y = 0.f;
#pragma unroll
        for (int s = 0; s < DS_; ++s) {
            h[s] = h[s] * expf(dtv * Aa[s]) + du * xd[l][48 + s];
            y = fmaf(h[s], xd[l][64 + s], y);
        }
        float zv = b2f(xz[base * 6144 + dir * 3072 + 1536 + ch]);
        ucy[uoff] = bf16rn((y + Dv * ucv) * (zv * sigm(zv)));
    }
}

// ---------------- block reduce helper ----------------
__device__ __forceinline__ float block_sum(float v)
{
    __shared__ float sd[4];
#pragma unroll
    for (int o = 1; o < 64; o <<= 1) v += __shfl_xor(v, o, 64);
    int lane = threadIdx.x & 63, wid = threadIdx.x >> 6;
    if (lane == 0) sd[wid] = v;
    __syncthreads();
    v = sd[0] + sd[1] + sd[2] + sd[3];
    __syncthreads();
    return v;
}

__global__ __launch_bounds__(256) void ln_residual_kernel(
    const float* __restrict__ xo, float* __restrict__ x,
    unsigned short* __restrict__ xbf,
    const float* __restrict__ g, const float* __restrict__ bt)
{
    int row = blockIdx.x;
    const float* pa = xo + (size_t)row * D_;
    float* px = x + (size_t)row * D_;
    float v[3];
    float s = 0.f;
#pragma unroll
    for (int i = 0; i < 3; ++i) { int d = threadIdx.x + 256 * i; v[i] = pa[d] + px[d]; s += v[i]; }
    float mean = block_sum(s) * (1.f / (float)D_);
    float sq = 0.f;
#pragma unroll
    for (int i = 0; i < 3; ++i) { float t = v[i] - mean; sq += t * t; }
    float var = block_sum(sq) * (1.f / (float)D_);
    float inv = rsqrtf(var + EPS_);
#pragma unroll
    for (int i = 0; i < 3; ++i) {
        int d = threadIdx.x + 256 * i;
        float o = (v[i] - mean) * inv * g[d] + bt[d];
        px[d] = o;
        xbf[(size_t)row * D_ + d] = bf16rn(o);
    }
}

__global__ __launch_bounds__(256) void ln_out_kernel(
    const float* __restrict__ x, const float* __restrict__ g,
    const float* __restrict__ bt, unsigned short* __restrict__ znorm)
{
    int row = blockIdx.x;
    int b = row / 3, p = row % 3;
    const float* pa = x + ((size_t)(b * L_ + 2 + p)) * D_;
    float v[3];
    float s = 0.f;
#pragma unroll
    for (int i = 0; i < 3; ++i) { int d = threadIdx.x + 256 * i; v[i] = pa[d]; s += v[i]; }
    float mean = block_sum(s) * (1.f / (float)D_);
    float sq = 0.f;
#pragma unroll
    for (int i = 0; i < 3; ++i) { float t = v[i] - mean; sq += t * t; }
    float var = block_sum(sq) * (1.f / (float)D_);
    float inv = rsqrtf(var + EPS_);
#pragma unroll
    for (int i = 0; i < 3; ++i) {
        int d = threadIdx.x + 256 * i;
        znorm[(size_t)row * D_ + d] = bf16rn((v[i] - mean) * inv * g[d] + bt[d]);
    }
}

extern "C" void kernel_launch(void* const* d_in, const int* in_sizes, int n_in,
                              void* d_out, int out_size, void* d_ws, size_t ws_size,
                              hipStream_t stream)
{
    const float* z_noisy  = (const float*)d_in[0];
    const float* text_emb = (const float*)d_in[1];
    const float* zin_b    = (const float*)d_in[3];
    const float* tin_b    = (const float*)d_in[5];
    const float* time_b   = (const float*)d_in[7];
    const float* part_emb = (const float*)d_in[8];
    const float* local_b  = (const float*)d_in[10];
    const float* f_b      = (const float*)d_in[12];
    const float* fuse_b   = (const float*)d_in[14];
    const float* final_b  = (const float*)d_in[16];
    const float* ln_g     = (const float*)d_in[17];
    const float* ln_b     = (const float*)d_in[18];
    const float* m_conv_w = (const float*)d_in[20];
    const float* m_conv_b = (const float*)d_in[21];
    const float* m_xproj_w= (const float*)d_in[22];
    const float* m_dt_w   = (const float*)d_in[23];
    const float* m_dt_b   = (const float*)d_in[24];
    const float* m_Alog   = (const float*)d_in[25];
    const float* m_Dp     = (const float*)d_in[26];
    const float* oln_g    = (const float*)d_in[28];
    const float* oln_b    = (const float*)d_in[29];
    const float* zout_b   = (const float*)d_in[31];
    const int*   timestep = (const int*)d_in[32];

    char* wsb = (char*)d_ws;
    unsigned short* wbf   = (unsigned short*)(wsb + OB_WBF);
    unsigned short* xpp   = (unsigned short*)(wsb + OB_XPP);
    unsigned short* tembb = (unsigned short*)(wsb + OB_TEMB);
    unsigned short* znormb= (unsigned short*)(wsb + OB_ZNORM);
    unsigned short* xbf   = (unsigned short*)(wsb + OB_XBF);
    unsigned short* tcbf  = (unsigned short*)(wsb + OB_TCBF);
    unsigned short* cat1b = (unsigned short*)(wsb + OB_CAT1);
    unsigned short* xtbf  = (unsigned short*)(wsb + OB_XTBF);
    unsigned short* xzbf  = (unsigned short*)(wsb + OB_XZBF);
    unsigned short* ucy   = (unsigned short*)(wsb + OB_UCY);
    unsigned short* cat2b = (unsigned short*)(wsb + OB_CAT2);
    float* x     = (float*)(wsb + OB_X);
    float* tc    = (float*)(wsb + OB_TC);
    float* tcf   = (float*)(wsb + OB_TCF);
    float* zfeat = (float*)(wsb + OB_ZFEAT);
    float* xo    = (float*)(wsb + OB_XO);
    float* part  = (float*)(wsb + OB_PART);

    unsigned short* local_bf = wbf + WO_LOCAL;
    unsigned short* f_bf     = wbf + WO_F;
    unsigned short* fuse_bf  = wbf + WO_FUSE;
    unsigned short* final_bf = wbf + WO_FINAL;
    unsigned short* in_bf    = wbf + WO_IN;
    unsigned short* out_bf   = wbf + WO_OUT;
    unsigned short* zin_bf   = wbf + WO_ZIN;
    unsigned short* tin_bf   = wbf + WO_TIN;
    unsigned short* time_bf  = wbf + WO_TIME;
    unsigned short* zout_bf  = wbf + WO_ZOUT;
    unsigned short* znz_bf   = wbf + WO_ZNOISY;
    unsigned short* text_bf  = wbf + WO_TEXT;

    auto ew = [&](int n) { return dim3((n + 255) / 256); };

    // ---------- conversion pass ----------
    CvtArgs ca;
    ca.s[0] = (const float*)d_in[9];   // local_w
    ca.s[1] = (const float*)d_in[11];  // f_w
    ca.s[2] = (const float*)d_in[13];  // fuse_w
    ca.s[3] = (const float*)d_in[15];  // final_w
    ca.s[4] = (const float*)d_in[19];  // m_in_w
    ca.s[5] = (const float*)d_in[27];  // m_out_w
    ca.s[6] = (const float*)d_in[2];   // zin_w
    ca.s[7] = (const float*)d_in[4];   // tin_w
    ca.s[8] = (const float*)d_in[6];   // time_w
    ca.s[9] = (const float*)d_in[30];  // zout_w
    ca.s[10] = z_noisy;
    ca.s[11] = text_emb;
    hipLaunchKernelGGL(cvt_kernel, dim3(WO_END / 16 / 256), dim3(256), 0, stream, ca, wbf);
    hipLaunchKernelGGL(xpad_kernel, dim3(12 * 128 * 1536 / 8 / 256), dim3(256), 0, stream,
                       m_xproj_w, xpp);
    hipLaunchKernelGGL(temb_kernel, ew(B_ * 384), dim3(256), 0, stream, timestep, tembb);

    auto g64 = [&](const unsigned short* A, int lda, const unsigned short* W, int wld,
                   const float* bias, const float* a0, const float* a1,
                   void* C, int ldc, int Mm, int Nn, int Kk, int epi, int ncap, int cd,
                   int gz, int zsplit, unsigned long long zA, unsigned long long zW,
                   unsigned long long zC) {
        dim3 g(Nn / 64, Mm / 64, gz);
        if (cd == 1)
            gemm_bf16_kernel<64, 64, 1><<<g, dim3(256), 0, stream>>>(
                A, lda, W, wld, bias, a0, a1, C, ldc, Mm, Nn, Kk, epi, ncap, zsplit, zA, zW, zC);
        else
            gemm_bf16_kernel<64, 64, 0><<<g, dim3(256), 0, stream>>>(
                A, lda, W, wld, bias, a0, a1, C, ldc, Mm, Nn, Kk, epi, ncap, zsplit, zA, zW, zC);
    };

    // ---------- embedding ----------
    g64(tembb, D_, time_bf, D_, time_b, nullptr, nullptr, x, L_ * D_, B_, D_, D_, 0, D_, 1,
        1, 1, 0, 0, 0);
    g64(text_bf, TXT_, tin_bf, TXT_, tin_b, nullptr, nullptr, x + D_, L_ * D_, B_, D_, TXT_, 0, D_, 1,
        1, 1, 0, 0, 0);
    g64(znz_bf, LAT_, zin_bf, LAT_, zin_b, nullptr, nullptr, zfeat, D_, B_ * NP_, D_, LAT_, 0, D_, 1,
        1, 1, 0, 0, 0);
    hipLaunchKernelGGL(finalize_embed_kernel, ew(B_ * L_ * D_), dim3(256), 0, stream,
                       x, xbf, zfeat, part_emb, tc, tcbf);

    // ---------- layers ----------
    for (int i = 0; i < NL_; ++i) {
        g64(xbf, D_, local_bf + (size_t)i * D_ * D_, D_, local_b + (size_t)i * D_,
            nullptr, nullptr, cat1b, 2 * D_, M_, D_, D_, 1, D_, 0, 1, 1, 0, 0, 0);
        g64(tcbf, D_, f_bf + (size_t)i * D_ * 2 * D_ + D_, 2 * D_, f_b + (size_t)i * D_,
            nullptr, nullptr, tcf, D_, B_, D_, D_, 0, D_, 1, 1, 1, 0, 0, 0);
        g64(cat1b, 2 * D_, f_bf + (size_t)i * D_ * 2 * D_, 2 * D_, nullptr,
            tcf, tc, cat1b + D_, 2 * D_, M_, D_, D_, 3, D_, 0, 1, 1, 0, 0, 0);
        g64(cat1b, 2 * D_, fuse_bf + (size_t)i * D_ * 2 * D_, 2 * D_, fuse_b + (size_t)i * D_,
            nullptr, nullptr, xtbf, D_, M_, D_, 2 * D_, 0, D_, 0, 1, 1, 0, 0, 0);

        // xz = xt @ [in_w0; in_w1]^T  (1280 x 6144) ; layer stride 4718592, ldc 6144
        {
            dim3 g(6144 / 128, M_ / 64, 1);
            gemm_bf16_kernel<64, 128, 0><<<g, dim3(256), 0, stream>>>(
                xtbf, D_, in_bf + (size_t)i * 4718592ull, D_, nullptr, nullptr, nullptr,
                xzbf, 6144, M_, 6144, D_, 0, 6144, 1, 0, 0, 0);
        }
        hipLaunchKernelGGL(conv_silu_kernel, ew(2 * M_ * DI_), dim3(256), 0, stream,
                           xzbf, m_conv_w + (size_t)i * 2 * DI_ * DC_,
                           m_conv_b + (size_t)i * 2 * DI_, ucy);
        {
            dim3 g(128 / 64, M_ / 64, 16);
            gemm_bf16_kernel<64, 64, 1><<<g, dim3(256), 0, stream>>>(
                ucy, DI_, xpp + (size_t)i * 2 * 128 * DI_, DI_, nullptr, nullptr, nullptr,
                part, 80, M_, 128, 192, 0, 80,
                8, (unsigned long long)M_ * DI_, (unsigned long long)128 * DI_,
                (unsigned long long)M_ * 80);
        }
        hipLaunchKernelGGL(dtscan_kernel, dim3(DI_ / 256, B_, 2), dim3(256), 0, stream,
                           part, ucy, xzbf,
                           m_dt_w + (size_t)i * 2 * DI_ * DTR_, m_dt_b + (size_t)i * 2 * DI_,
                           m_Alog + (size_t)i * 2 * DI_ * DS_, m_Dp + (size_t)i * 2 * DI_);
        g64(ucy, DI_, out_bf + (size_t)i * 2 * D_ * DI_, DI_, nullptr, nullptr, nullptr,
            cat2b, 2 * D_, M_, D_, DI_, 0, D_, 0,
            2, 1, (unsigned long long)M_ * DI_, (unsigned long long)D_ * DI_, 768ull);
        g64(cat2b, 2 * D_, final_bf + (size_t)i * D_ * 2 * D_, 2 * D_, final_b + (size_t)i * D_,
            nullptr, nullptr, xo, D_, M_, D_, 2 * D_, 0, D_, 1, 1, 1, 0, 0, 0);
        hipLaunchKernelGGL(ln_residual_kernel, dim3(M_), dim3(256), 0, stream,
                           xo, x, xbf, ln_g + (size_t)i * D_, ln_b + (size_t)i * D_);
    }

    // ---------- output head ----------
    hipLaunchKernelGGL(ln_out_kernel, dim3(B_ * NP_), dim3(256), 0, stream,
                       x, oln_g, oln_b, znormb);
    g64(znormb, D_, zout_bf, D_, zout_b, nullptr, nullptr,
        (float*)d_out, LAT_, B_ * NP_, LAT_, D_, 0, LAT_, 1, 1, 1, 0, 0, 0);
}